// Round 1
// baseline (532.923 us; speedup 1.0000x reference)
//
#include <hip/hip_runtime.h>

// ---------------- problem constants ----------------
#define Kc 8
#define Bc 64
#define Tc 128
#define Yc 128
#define Xc 64
#define Hc 256
#define Rc 8192   // B*T

typedef unsigned short u16;
typedef unsigned int u32;
typedef __attribute__((ext_vector_type(8))) short short8;  // 8 bf16 (4 VGPR)
typedef __attribute__((ext_vector_type(4))) float f32x4;   // MFMA C/D

// ---------------- ws layout (u16 element offsets) ----------------
#define OFF_DATA 0L         // data bf16        [8192][128]
#define OFF_YWIH 1048576L   // y_Wih bf16       [8][256][128]
#define OFF_YWHH 1310720L   // y_Whh bf16       [8][256][256]
#define OFF_YWMU 1835008L   // y_Wmu bf16       [8][64][256]
#define OFF_XWIH 1966080L   // x_Wih bf16       [8][256][64]
#define OFF_XWHH 2097152L   // x_Whh bf16       [8][256][256]
#define OFF_M2   2621440L   // M2 = W2@dsW bf16 [16(pad)][2048]
#define OFF_QX   2654208L   // q_x bf16         [8][8192][64]
#define OFF_BUF1 6848512L   // xW_y -> h_y bf16 [8][8192][256] (in-place)
#define OFF_BUF2 23625728L  // xW_x -> h_x bf16 [8][8192][256] (in-place)
#define U16_BYTES 80805888L
// f32 region (after u16 region)
#define FO_YB 0L      // y bias (bih+bhh) [8][256]
#define FO_XB 2048L   // x bias           [8][256]
#define FO_CB 4096L   // combiner const   [16]
#define FO_A2 4112L   // A2 = W2@W1       [8][8]
#define FO_C  8192L   // c buffer         [8192][8]
#define FO_W  73728L  // sparsemax w      [8192][8]

// ---------------- output layout (f32 elements) ----------------
#define O_XS  0L        // x_sample   [64][128][64]
#define O_QMU 524288L   // q_x_mu     [8][64][128][64]
#define O_QLV 4718592L  // q_x_logvar [8][64][128][64] (zeros)
#define O_ZS  8912896L  // z_sample   [64][128][8]
#define O_ZL  8978432L  // z_logits   [64][128][8]

// ---------------- helpers ----------------
__device__ __forceinline__ u16 f2bf(float f) {
  union { float f; u32 u; } v; v.f = f;
  u32 u = v.u;
  return (u16)((u + 0x7FFFu + ((u >> 16) & 1u)) >> 16);  // RNE
}
__device__ __forceinline__ float bf2f(u16 h) {
  union { u32 u; float f; } v; v.u = ((u32)h) << 16;
  return v.f;
}
__device__ __forceinline__ f32x4 mfma16(short8 a, short8 b, f32x4 c) {
  return __builtin_amdgcn_mfma_f32_16x16x32_bf16(a, b, c, 0, 0, 0);
}
// swizzled element index into a [16][256] bf16 LDS tile (XOR 16B granules per row)
__device__ __forceinline__ int swz(int m, int j) {
  return m * 256 + ((((j >> 3) ^ (m & 7)) << 3) | (j & 7));
}

// ---------------- P1: dtype conversions, biases, zero logvar ----------------
__global__ void k_prep(const float* __restrict__ data, const float* __restrict__ yWih,
                       const float* __restrict__ yWhh, const float* __restrict__ yWmu,
                       const float* __restrict__ xWih, const float* __restrict__ xWhh,
                       const float* __restrict__ ybih, const float* __restrict__ ybhh,
                       const float* __restrict__ xbih, const float* __restrict__ xbhh,
                       u16* __restrict__ W, float* __restrict__ F, float* __restrict__ out)
{
  long tid = (long)blockIdx.x * blockDim.x + threadIdx.x;
  long stride = (long)gridDim.x * blockDim.x;
  for (long i = tid; i < 1048576L; i += stride) W[OFF_DATA + i] = f2bf(data[i]);
  for (long i = tid; i < 262144L;  i += stride) W[OFF_YWIH + i] = f2bf(yWih[i]);
  for (long i = tid; i < 524288L;  i += stride) W[OFF_YWHH + i] = f2bf(yWhh[i]);
  for (long i = tid; i < 131072L;  i += stride) W[OFF_YWMU + i] = f2bf(yWmu[i]);
  for (long i = tid; i < 131072L;  i += stride) W[OFF_XWIH + i] = f2bf(xWih[i]);
  for (long i = tid; i < 524288L;  i += stride) W[OFF_XWHH + i] = f2bf(xWhh[i]);
  for (long i = tid; i < 2048L;    i += stride) F[FO_YB + i] = ybih[i] + ybhh[i];
  for (long i = tid; i < 2048L;    i += stride) F[FO_XB + i] = xbih[i] + xbhh[i];
  for (long i = tid; i < 4194304L; i += stride) out[O_QLV + i] = 0.0f;
}

// ---------------- P2: combiner collapse  M2 = W2@dsW,  A2 = W2@W1,  cbias ----------------
__global__ void k_prep2(const float* __restrict__ dsW, const float* __restrict__ dsb,
                        const float* __restrict__ W1, const float* __restrict__ b1,
                        const float* __restrict__ W2, const float* __restrict__ b2,
                        u16* __restrict__ W, float* __restrict__ F)
{
  if (blockIdx.x < 128) {  // M2 [16][2048] (rows >=8 zero-padded)
    long i = (long)blockIdx.x * 256 + threadIdx.x;   // 0..32767
    int k2 = (int)(i >> 11), ki = (int)(i & 2047);
    float s = 0.0f;
    if (k2 < 8) {
      for (int j = 0; j < 256; ++j) s += W2[k2 * 256 + j] * dsW[(long)j * 2048 + ki];
    }
    W[OFF_M2 + i] = f2bf(s);
  } else {  // blockIdx.x == 128
    int t = threadIdx.x;
    if (t < 64) {            // A2[k2][k1] = sum_j W2[k2,j] W1[j,k1]
      int k2 = t >> 3, k1 = t & 7;
      float s = 0.0f;
      for (int j = 0; j < 256; ++j) s += W2[k2 * 256 + j] * W1[j * 8 + k1];
      F[FO_A2 + t] = s;
    } else if (t < 80) {     // cbias[k2] = W2@(dsb+b1) + b2   (pad to 16)
      int k2 = t - 64;
      float s = 0.0f;
      if (k2 < 8) {
        for (int j = 0; j < 256; ++j) s += W2[k2 * 256 + j] * (dsb[j] + b1[j]);
        s += b2[k2];
      }
      F[FO_CB + k2] = s;
    }
  }
}

// ---------------- G1: xW_y = data @ y_Wih^T + ybias  -> buf1 (bf16) ----------------
__global__ __launch_bounds__(256) void k_g1(const u16* __restrict__ W, const float* __restrict__ F,
                                            u16* __restrict__ buf1)
{
  const int k = blockIdx.y, m0 = blockIdx.x * 16;
  const int tid = threadIdx.x, wv = tid >> 6, l = tid & 63, lr = l & 15, lk = l >> 4;
  const int n0 = wv * 64;
  const u16* A = W + OFF_DATA + (long)(m0 + lr) * 128 + lk * 8;
  const u16* Bw = W + OFF_YWIH + (long)k * 256 * 128;
  f32x4 acc[4];
#pragma unroll
  for (int nt = 0; nt < 4; ++nt) {
    float bv = F[FO_YB + k * 256 + n0 + nt * 16 + lr];
    acc[nt] = (f32x4){bv, bv, bv, bv};
  }
#pragma unroll
  for (int kk = 0; kk < 4; ++kk) {
    short8 a = *(const short8*)(A + kk * 32);
#pragma unroll
    for (int nt = 0; nt < 4; ++nt) {
      short8 b = *(const short8*)(Bw + (long)(n0 + nt * 16 + lr) * 128 + kk * 32 + lk * 8);
      acc[nt] = mfma16(a, b, acc[nt]);
    }
  }
  u16* outp = buf1 + (long)k * Rc * 256;
#pragma unroll
  for (int nt = 0; nt < 4; ++nt)
#pragma unroll
    for (int r = 0; r < 4; ++r)
      outp[(long)(m0 + lk * 4 + r) * 256 + n0 + nt * 16 + lr] = f2bf(acc[nt][r]);
}

// ---------------- R: backward ReLU RNN (shared y/x).  In-place xW -> h. ----------------
// grid (4 b-splits, 8 k), 256 thr. Whh fragments resident in 128 VGPR/lane.
__global__ __launch_bounds__(256, 1) void k_rnn(u16* __restrict__ hbuf,
                                                const u16* __restrict__ Whh,
                                                const float* __restrict__ h0)
{
  const int k = blockIdx.y, b0 = blockIdx.x * 16;
  const int tid = threadIdx.x, wv = tid >> 6, l = tid & 63, lr = l & 15, lk = l >> 4;
  const int n0 = wv * 64;
  __shared__ __align__(16) u16 hlds[16 * 256];

  short8 Bf[4][8];
  {
    const u16* Wk = Whh + (long)k * 65536;
#pragma unroll
    for (int nt = 0; nt < 4; ++nt)
#pragma unroll
      for (int kk = 0; kk < 8; ++kk)
        Bf[nt][kk] = *(const short8*)(Wk + (long)(n0 + nt * 16 + lr) * 256 + kk * 32 + lk * 8);
  }
  {
    int j = tid;
    u16 hv = f2bf(h0[k * 256 + j]);
#pragma unroll
    for (int m = 0; m < 16; ++m) hlds[swz(m, j)] = hv;
  }
  __syncthreads();

  u16* base = hbuf + (long)k * Rc * 256;
  u16 xw[16];
#pragma unroll
  for (int nt = 0; nt < 4; ++nt)
#pragma unroll
    for (int r = 0; r < 4; ++r)
      xw[nt * 4 + r] = base[((long)(b0 + lk * 4 + r) * Tc + (Tc - 1)) * 256 + n0 + nt * 16 + lr];

  for (int t = Tc - 1; t >= 0; --t) {
    u16 xwn[16];
    if (t > 0) {
#pragma unroll
      for (int nt = 0; nt < 4; ++nt)
#pragma unroll
        for (int r = 0; r < 4; ++r)
          xwn[nt * 4 + r] = base[((long)(b0 + lk * 4 + r) * Tc + (t - 1)) * 256 + n0 + nt * 16 + lr];
    }
    f32x4 acc[4];
#pragma unroll
    for (int nt = 0; nt < 4; ++nt) {
      acc[nt][0] = bf2f(xw[nt * 4 + 0]);
      acc[nt][1] = bf2f(xw[nt * 4 + 1]);
      acc[nt][2] = bf2f(xw[nt * 4 + 2]);
      acc[nt][3] = bf2f(xw[nt * 4 + 3]);
    }
#pragma unroll
    for (int kk = 0; kk < 8; ++kk) {
      short8 a = *(const short8*)&hlds[lr * 256 + (((kk * 4 + lk) ^ (lr & 7)) << 3)];
#pragma unroll
      for (int nt = 0; nt < 4; ++nt) acc[nt] = mfma16(a, Bf[nt][kk], acc[nt]);
    }
    __syncthreads();
#pragma unroll
    for (int nt = 0; nt < 4; ++nt)
#pragma unroll
      for (int r = 0; r < 4; ++r) {
        int m = lk * 4 + r, j = n0 + nt * 16 + lr;
        u16 hv = f2bf(fmaxf(acc[nt][r], 0.0f));
        hlds[swz(m, j)] = hv;
        base[((long)(b0 + m) * Tc + t) * 256 + j] = hv;
      }
    __syncthreads();
#pragma unroll
    for (int i = 0; i < 16; ++i) xw[i] = xwn[i];
  }
}

// ---------------- G2: q_x_mu = h_y @ Wmu^T + bmu (f32 out), q_x = mu+eps (bf16 ws) ----------------
__global__ __launch_bounds__(256) void k_g2(const u16* __restrict__ W, const u16* __restrict__ hy,
                                            const float* __restrict__ bmu, const float* __restrict__ eps_qx,
                                            float* __restrict__ out, u16* __restrict__ qx)
{
  const int k = blockIdx.y;
  const int m0 = blockIdx.x * 64 + (threadIdx.x >> 6) * 16;
  const int l = threadIdx.x & 63, lr = l & 15, lk = l >> 4;
  const u16* A = hy + ((long)k * Rc + m0 + lr) * 256 + lk * 8;
  const u16* Bw = W + OFF_YWMU + (long)k * 64 * 256;
  f32x4 acc[4];
#pragma unroll
  for (int nt = 0; nt < 4; ++nt) {
    float bv = bmu[k * 64 + nt * 16 + lr];
    acc[nt] = (f32x4){bv, bv, bv, bv};
  }
#pragma unroll
  for (int kk = 0; kk < 8; ++kk) {
    short8 a = *(const short8*)(A + kk * 32);
#pragma unroll
    for (int nt = 0; nt < 4; ++nt) {
      short8 b = *(const short8*)(Bw + (long)(nt * 16 + lr) * 256 + kk * 32 + lk * 8);
      acc[nt] = mfma16(a, b, acc[nt]);
    }
  }
#pragma unroll
  for (int nt = 0; nt < 4; ++nt)
#pragma unroll
    for (int r = 0; r < 4; ++r) {
      long idx = ((long)k * Rc + m0 + lk * 4 + r) * 64 + nt * 16 + lr;
      float v = acc[nt][r];
      out[O_QMU + idx] = v;
      qx[idx] = f2bf(v + eps_qx[idx]);
    }
}

// ---------------- G3: xW_x = q_x @ x_Wih^T + xbias -> buf2 (bf16) ----------------
__global__ __launch_bounds__(256) void k_g3(const u16* __restrict__ W, const u16* __restrict__ qx,
                                            const float* __restrict__ F, u16* __restrict__ buf2)
{
  const int k = blockIdx.y, m0 = blockIdx.x * 16;
  const int tid = threadIdx.x, wv = tid >> 6, l = tid & 63, lr = l & 15, lk = l >> 4;
  const int n0 = wv * 64;
  const u16* A = qx + ((long)k * Rc + m0 + lr) * 64 + lk * 8;
  const u16* Bw = W + OFF_XWIH + (long)k * 256 * 64;
  f32x4 acc[4];
#pragma unroll
  for (int nt = 0; nt < 4; ++nt) {
    float bv = F[FO_XB + k * 256 + n0 + nt * 16 + lr];
    acc[nt] = (f32x4){bv, bv, bv, bv};
  }
#pragma unroll
  for (int kk = 0; kk < 2; ++kk) {
    short8 a = *(const short8*)(A + kk * 32);
#pragma unroll
    for (int nt = 0; nt < 4; ++nt) {
      short8 b = *(const short8*)(Bw + (long)(n0 + nt * 16 + lr) * 64 + kk * 32 + lk * 8);
      acc[nt] = mfma16(a, b, acc[nt]);
    }
  }
  u16* outp = buf2 + (long)k * Rc * 256;
#pragma unroll
  for (int nt = 0; nt < 4; ++nt)
#pragma unroll
    for (int r = 0; r < 4; ++r)
      outp[(long)(m0 + lk * 4 + r) * 256 + n0 + nt * 16 + lr] = f2bf(acc[nt][r]);
}

// ---------------- G4: c = summary @ M2^T + cbias  (N=8, K=2048) ----------------
__global__ __launch_bounds__(256) void k_g4(const u16* __restrict__ W, const u16* __restrict__ hx,
                                            const float* __restrict__ F, float* __restrict__ cbuf)
{
  const int m0 = blockIdx.x * 64 + (threadIdx.x >> 6) * 16;
  const int l = threadIdx.x & 63, lr = l & 15, lk = l >> 4;
  const u16* M2 = W + OFF_M2;
  float bv = F[FO_CB + lr];
  f32x4 acc = (f32x4){bv, bv, bv, bv};
#pragma unroll 8
  for (int kk = 0; kk < 64; ++kk) {
    int k8 = kk >> 3, ko = kk & 7;
    short8 a = *(const short8*)(hx + ((long)k8 * Rc + m0 + lr) * 256 + ko * 32 + lk * 8);
    short8 b = *(const short8*)(M2 + (long)lr * 2048 + kk * 32 + lk * 8);
    acc = mfma16(a, b, acc);
  }
  if (lr < 8) {
#pragma unroll
    for (int r = 0; r < 4; ++r)
      cbuf[(long)(m0 + lk * 4 + r) * 8 + lr] = acc[r];
  }
}

// ---------------- S5a: z chain (one wave per batch element) ----------------
#define CASD(a, b) { float _hi = fmaxf(a, b), _lo = fminf(a, b); a = _hi; b = _lo; }
__global__ __launch_bounds__(256) void k_zchain(const float* __restrict__ F, const float* __restrict__ cbuf,
                                                const float* __restrict__ eps_z, const float* __restrict__ zq0,
                                                float* __restrict__ out, float* __restrict__ wbuf)
{
  const int wv = threadIdx.x >> 6, l = threadIdx.x & 63;
  const int b = blockIdx.x * 4 + wv;
  __shared__ float cl[4][1024];
  __shared__ float el[4][1024];
  for (int i = l; i < 1024; i += 64) cl[wv][i] = cbuf[(long)b * 1024 + i];
  for (int i = l; i < 1024; i += 64) {
    int t = i >> 3, kk = i & 7;
    el[wv][i] = eps_z[(long)t * (Bc * Kc) + b * 8 + kk];
  }
  float a2 = F[FO_A2 + l];   // A2[l>>3][l&7]
  __syncthreads();

  float z = zq0[l & 7];      // every lane holds z_prev[l&7]
  for (int t = 0; t < Tc; ++t) {
    float p = a2 * z;
    p += __shfl_xor(p, 1, 64);
    p += __shfl_xor(p, 2, 64);
    p += __shfl_xor(p, 4, 64);                  // group g=l>>3 holds sum_k1 A2[g][k1] z[k1]
    float zmu_l = __shfl(p, (l & 7) * 8, 64);   // lane l gets zmu_lin[l&7]
    float zl = zmu_l + cl[wv][t * 8 + (l & 7)]; // z_logits
    float zt = zl + el[wv][t * 8 + (l & 7)];    // z_sample

    // sparsemax over 8 values (all lanes redundantly)
    float v0 = __shfl(zt, 0, 64), v1 = __shfl(zt, 1, 64), v2 = __shfl(zt, 2, 64), v3 = __shfl(zt, 3, 64);
    float v4 = __shfl(zt, 4, 64), v5 = __shfl(zt, 5, 64), v6 = __shfl(zt, 6, 64), v7 = __shfl(zt, 7, 64);
    CASD(v0, v1); CASD(v2, v3); CASD(v4, v5); CASD(v6, v7);
    CASD(v0, v2); CASD(v1, v3); CASD(v4, v6); CASD(v5, v7);
    CASD(v1, v2); CASD(v5, v6);
    CASD(v0, v4); CASD(v1, v5); CASD(v2, v6); CASD(v3, v7);
    CASD(v2, v4); CASD(v3, v5);
    CASD(v1, v2); CASD(v3, v4); CASD(v5, v6);   // v0 >= v1 >= ... >= v7
    float s0 = v0, s1 = s0 + v1, s2 = s1 + v2, s3 = s2 + v3;
    float s4 = s3 + v4, s5 = s4 + v5, s6 = s5 + v6, s7 = s6 + v7;
    int kz = 1;
    kz += (2.0f * v1 > s1 - 1.0f) ? 1 : 0;
    kz += (3.0f * v2 > s2 - 1.0f) ? 1 : 0;
    kz += (4.0f * v3 > s3 - 1.0f) ? 1 : 0;
    kz += (5.0f * v4 > s4 - 1.0f) ? 1 : 0;
    kz += (6.0f * v5 > s5 - 1.0f) ? 1 : 0;
    kz += (7.0f * v6 > s6 - 1.0f) ? 1 : 0;
    kz += (8.0f * v7 > s7 - 1.0f) ? 1 : 0;
    float csel = s0 - 1.0f;
    csel = (kz > 1) ? s1 - 1.0f : csel;
    csel = (kz > 2) ? s2 - 1.0f : csel;
    csel = (kz > 3) ? s3 - 1.0f : csel;
    csel = (kz > 4) ? s4 - 1.0f : csel;
    csel = (kz > 5) ? s5 - 1.0f : csel;
    csel = (kz > 6) ? s6 - 1.0f : csel;
    csel = (kz > 7) ? s7 - 1.0f : csel;
    float tau = csel / (float)kz;
    float wk = fmaxf(zt - tau, 0.0f);

    if (l < 8) {
      long r = (long)b * Tc + t;
      out[O_ZL + r * 8 + l] = zl;
      out[O_ZS + r * 8 + l] = zt;
      wbuf[r * 8 + l] = wk;
    }
    z = zt;
  }
}

// ---------------- S5b: x_sample = sum_k w * mu + eps_x ----------------
__global__ void k_xsample(const float* __restrict__ wbuf, const float* __restrict__ eps_x,
                          float* __restrict__ out)
{
  long idx = (long)blockIdx.x * 256 + threadIdx.x;
  if (idx >= (long)Rc * Xc) return;
  long r = idx >> 6;          // b*T + t
  int x = (int)(idx & 63);
  long b = r >> 7;
  long t = r & 127;
  float s = eps_x[(t * Bc + b) * 64 + x];
#pragma unroll
  for (int k = 0; k < 8; ++k)
    s += wbuf[r * 8 + k] * out[O_QMU + ((long)k * Rc + r) * 64 + x];
  out[O_XS + idx] = s;
}

// ---------------- launch ----------------
extern "C" void kernel_launch(void* const* d_in, const int* in_sizes, int n_in,
                              void* d_out, int out_size, void* d_ws, size_t ws_size,
                              hipStream_t stream) {
  (void)in_sizes; (void)n_in; (void)out_size; (void)ws_size;
  const float* data   = (const float*)d_in[0];
  const float* eps_qx = (const float*)d_in[1];
  const float* eps_z  = (const float*)d_in[2];
  const float* eps_x  = (const float*)d_in[3];
  const float* yWih   = (const float*)d_in[4];
  const float* yWhh   = (const float*)d_in[5];
  const float* ybih   = (const float*)d_in[6];
  const float* ybhh   = (const float*)d_in[7];
  const float* yh0    = (const float*)d_in[8];
  const float* yWmu   = (const float*)d_in[9];
  const float* ybmu   = (const float*)d_in[10];
  const float* xWih   = (const float*)d_in[11];
  const float* xWhh   = (const float*)d_in[12];
  const float* xbih   = (const float*)d_in[13];
  const float* xbhh   = (const float*)d_in[14];
  const float* xh0    = (const float*)d_in[15];
  const float* dsW    = (const float*)d_in[16];
  const float* dsb    = (const float*)d_in[17];
  const float* cbW1   = (const float*)d_in[18];
  const float* cbb1   = (const float*)d_in[19];
  const float* cbW2   = (const float*)d_in[20];
  const float* cbb2   = (const float*)d_in[21];
  const float* zq0    = (const float*)d_in[22];

  u16*   W = (u16*)d_ws;
  float* F = (float*)((char*)d_ws + U16_BYTES);
  float* out = (float*)d_out;

  hipLaunchKernelGGL(k_prep, dim3(1024), dim3(256), 0, stream,
                     data, yWih, yWhh, yWmu, xWih, xWhh, ybih, ybhh, xbih, xbhh, W, F, out);
  hipLaunchKernelGGL(k_prep2, dim3(129), dim3(256), 0, stream,
                     dsW, dsb, cbW1, cbb1, cbW2, cbb2, W, F);
  hipLaunchKernelGGL(k_g1, dim3(512, 8), dim3(256), 0, stream, W, F, W + OFF_BUF1);
  hipLaunchKernelGGL(k_rnn, dim3(4, 8), dim3(256), 0, stream, W + OFF_BUF1, W + OFF_YWHH, yh0);
  hipLaunchKernelGGL(k_g2, dim3(128, 8), dim3(256), 0, stream,
                     W, W + OFF_BUF1, ybmu, eps_qx, out, W + OFF_QX);
  hipLaunchKernelGGL(k_g3, dim3(512, 8), dim3(256), 0, stream, W, W + OFF_QX, F, W + OFF_BUF2);
  hipLaunchKernelGGL(k_rnn, dim3(4, 8), dim3(256), 0, stream, W + OFF_BUF2, W + OFF_XWHH, xh0);
  hipLaunchKernelGGL(k_g4, dim3(128), dim3(256), 0, stream, W, W + OFF_BUF2, F, F + FO_C);
  hipLaunchKernelGGL(k_zchain, dim3(16), dim3(256), 0, stream, F, F + FO_C, eps_z, zq0, out, F + FO_W);
  hipLaunchKernelGGL(k_xsample, dim3(2048), dim3(256), 0, stream, F + FO_W, eps_x, out);
}

// Round 2
// 520.988 us; speedup vs baseline: 1.0229x; 1.0229x over previous
//
#include <hip/hip_runtime.h>

// ---------------- problem constants ----------------
#define Kc 8
#define Bc 64
#define Tc 128
#define Yc 128
#define Xc 64
#define Hc 256
#define Rc 8192   // B*T

typedef unsigned short u16;
typedef unsigned int u32;
typedef __attribute__((ext_vector_type(8))) short short8;  // 8 bf16 (4 VGPR)
typedef __attribute__((ext_vector_type(4))) float f32x4;   // MFMA C/D

// ---------------- ws layout (u16 element offsets) ----------------
#define OFF_DATA 0L         // data bf16        [8192][128]
#define OFF_YWIH 1048576L   // y_Wih bf16       [8][256][128]
#define OFF_YWHH 1310720L   // y_Whh bf16       [8][256][256]
#define OFF_YWMU 1835008L   // y_Wmu bf16       [8][64][256]
#define OFF_XWIH 1966080L   // x_Wih bf16       [8][256][64]
#define OFF_XWHH 2097152L   // x_Whh bf16       [8][256][256]
#define OFF_M2   2621440L   // M2 = W2@dsW bf16 [16(pad)][2048]
#define OFF_QX   2654208L   // q_x bf16         [8][8192][64]
#define OFF_BUF1 6848512L   // xW_y -> h_y bf16 [8][8192][256] (in-place)
#define OFF_BUF2 23625728L  // xW_x -> h_x bf16 [8][8192][256] (in-place)
#define U16_BYTES 80805888L
// f32 region (after u16 region)
#define FO_YB 0L      // y bias (bih+bhh) [8][256]
#define FO_XB 2048L   // x bias           [8][256]
#define FO_CB 4096L   // combiner const   [16]
#define FO_A2 4112L   // A2 = W2@W1       [8][8]
#define FO_C  8192L   // c buffer         [8192][8]
#define FO_W  73728L  // sparsemax w      [8192][8]

// ---------------- output layout (f32 elements) ----------------
#define O_XS  0L        // x_sample   [64][128][64]
#define O_QMU 524288L   // q_x_mu     [8][64][128][64]
#define O_QLV 4718592L  // q_x_logvar [8][64][128][64] (zeros)
#define O_ZS  8912896L  // z_sample   [64][128][8]
#define O_ZL  8978432L  // z_logits   [64][128][8]

// ---------------- helpers ----------------
__device__ __forceinline__ u16 f2bf(float f) {
  union { float f; u32 u; } v; v.f = f;
  u32 u = v.u;
  return (u16)((u + 0x7FFFu + ((u >> 16) & 1u)) >> 16);  // RNE
}
__device__ __forceinline__ float bf2f(u16 h) {
  union { u32 u; float f; } v; v.u = ((u32)h) << 16;
  return v.f;
}
__device__ __forceinline__ f32x4 mfma16(short8 a, short8 b, f32x4 c) {
  return __builtin_amdgcn_mfma_f32_16x16x32_bf16(a, b, c, 0, 0, 0);
}
// swizzled element index into a [16][256] bf16 LDS tile (XOR 16B granules per row)
__device__ __forceinline__ int swz(int m, int j) {
  return m * 256 + ((((j >> 3) ^ (m & 7)) << 3) | (j & 7));
}

// ---------------- P1: dtype conversions, biases, zero logvar ----------------
__global__ void k_prep(const float* __restrict__ data, const float* __restrict__ yWih,
                       const float* __restrict__ yWhh, const float* __restrict__ yWmu,
                       const float* __restrict__ xWih, const float* __restrict__ xWhh,
                       const float* __restrict__ ybih, const float* __restrict__ ybhh,
                       const float* __restrict__ xbih, const float* __restrict__ xbhh,
                       u16* __restrict__ W, float* __restrict__ F, float* __restrict__ out)
{
  long tid = (long)blockIdx.x * blockDim.x + threadIdx.x;
  long stride = (long)gridDim.x * blockDim.x;
  for (long i = tid; i < 1048576L; i += stride) W[OFF_DATA + i] = f2bf(data[i]);
  for (long i = tid; i < 262144L;  i += stride) W[OFF_YWIH + i] = f2bf(yWih[i]);
  for (long i = tid; i < 524288L;  i += stride) W[OFF_YWHH + i] = f2bf(yWhh[i]);
  for (long i = tid; i < 131072L;  i += stride) W[OFF_YWMU + i] = f2bf(yWmu[i]);
  for (long i = tid; i < 131072L;  i += stride) W[OFF_XWIH + i] = f2bf(xWih[i]);
  for (long i = tid; i < 524288L;  i += stride) W[OFF_XWHH + i] = f2bf(xWhh[i]);
  for (long i = tid; i < 2048L;    i += stride) F[FO_YB + i] = ybih[i] + ybhh[i];
  for (long i = tid; i < 2048L;    i += stride) F[FO_XB + i] = xbih[i] + xbhh[i];
  for (long i = tid; i < 4194304L; i += stride) out[O_QLV + i] = 0.0f;
}

// ---------------- P2: combiner collapse  M2 = W2@dsW,  A2 = W2@W1,  cbias ----------------
__global__ void k_prep2(const float* __restrict__ dsW, const float* __restrict__ dsb,
                        const float* __restrict__ W1, const float* __restrict__ b1,
                        const float* __restrict__ W2, const float* __restrict__ b2,
                        u16* __restrict__ W, float* __restrict__ F)
{
  if (blockIdx.x < 128) {  // M2 [16][2048] (rows >=8 zero-padded)
    long i = (long)blockIdx.x * 256 + threadIdx.x;   // 0..32767
    int k2 = (int)(i >> 11), ki = (int)(i & 2047);
    float s = 0.0f;
    if (k2 < 8) {
      for (int j = 0; j < 256; ++j) s += W2[k2 * 256 + j] * dsW[(long)j * 2048 + ki];
    }
    W[OFF_M2 + i] = f2bf(s);
  } else {  // blockIdx.x == 128
    int t = threadIdx.x;
    if (t < 64) {            // A2[k2][k1] = sum_j W2[k2,j] W1[j,k1]
      int k2 = t >> 3, k1 = t & 7;
      float s = 0.0f;
      for (int j = 0; j < 256; ++j) s += W2[k2 * 256 + j] * W1[j * 8 + k1];
      F[FO_A2 + t] = s;
    } else if (t < 80) {     // cbias[k2] = W2@(dsb+b1) + b2   (pad to 16)
      int k2 = t - 64;
      float s = 0.0f;
      if (k2 < 8) {
        for (int j = 0; j < 256; ++j) s += W2[k2 * 256 + j] * (dsb[j] + b1[j]);
        s += b2[k2];
      }
      F[FO_CB + k2] = s;
    }
  }
}

// ---------------- G1: xW_y = data @ y_Wih^T + ybias  -> buf1 (bf16) ----------------
__global__ __launch_bounds__(256) void k_g1(const u16* __restrict__ W, const float* __restrict__ F,
                                            u16* __restrict__ buf1)
{
  const int k = blockIdx.y, m0 = blockIdx.x * 16;
  const int tid = threadIdx.x, wv = tid >> 6, l = tid & 63, lr = l & 15, lk = l >> 4;
  const int n0 = wv * 64;
  const u16* A = W + OFF_DATA + (long)(m0 + lr) * 128 + lk * 8;
  const u16* Bw = W + OFF_YWIH + (long)k * 256 * 128;
  f32x4 acc[4];
#pragma unroll
  for (int nt = 0; nt < 4; ++nt) {
    float bv = F[FO_YB + k * 256 + n0 + nt * 16 + lr];
    acc[nt] = (f32x4){bv, bv, bv, bv};
  }
#pragma unroll
  for (int kk = 0; kk < 4; ++kk) {
    short8 a = *(const short8*)(A + kk * 32);
#pragma unroll
    for (int nt = 0; nt < 4; ++nt) {
      short8 b = *(const short8*)(Bw + (long)(n0 + nt * 16 + lr) * 128 + kk * 32 + lk * 8);
      acc[nt] = mfma16(a, b, acc[nt]);
    }
  }
  u16* outp = buf1 + (long)k * Rc * 256;
#pragma unroll
  for (int nt = 0; nt < 4; ++nt)
#pragma unroll
    for (int r = 0; r < 4; ++r)
      outp[(long)(m0 + lk * 4 + r) * 256 + n0 + nt * 16 + lr] = f2bf(acc[nt][r]);
}

// ---------------- R: backward ReLU RNN (shared y/x).  In-place xW -> h. ----------------
// grid (4 b-splits, 8 k), 512 thr (8 waves x 32-col stripes).
// Whh fragments resident in 64 VGPR/lane. Double-buffered swizzled h in LDS;
// raw s_barrier + lgkmcnt-only wait (prefetch/stores stay in flight).
__global__ __launch_bounds__(512, 1) void k_rnn(u16* __restrict__ hbuf,
                                                const u16* __restrict__ Whh,
                                                const float* __restrict__ h0)
{
  const int k = blockIdx.y, b0 = blockIdx.x * 16;
  const int tid = threadIdx.x, wv = tid >> 6, l = tid & 63, lr = l & 15, lk = l >> 4;
  const int n0 = wv * 32;
  __shared__ __align__(16) u16 hlds[2][16 * 256];

  // resident weight fragments: 2 n-tiles x 8 k-frags = 64 VGPR
  short8 Bf[2][8];
  {
    const u16* Wk = Whh + (long)k * 65536;
#pragma unroll
    for (int nt = 0; nt < 2; ++nt)
#pragma unroll
      for (int kk = 0; kk < 8; ++kk)
        Bf[nt][kk] = *(const short8*)(Wk + (long)(n0 + nt * 16 + lr) * 256 + kk * 32 + lk * 8);
  }
  if (tid < 256) {
    u16 hv = f2bf(h0[k * 256 + tid]);
#pragma unroll
    for (int m = 0; m < 16; ++m) hlds[0][swz(m, tid)] = hv;
  }

  u16* base = hbuf + (long)k * Rc * 256;
  u16 xw[8];
#pragma unroll
  for (int nt = 0; nt < 2; ++nt)
#pragma unroll
    for (int r = 0; r < 4; ++r)
      xw[nt * 4 + r] = base[((long)(b0 + lk * 4 + r) * Tc + (Tc - 1)) * 256 + n0 + nt * 16 + lr];

  __syncthreads();  // one-time full drain (init visible)

  int p = 0;
  for (int t = Tc - 1; t >= 0; --t) {
    u16 xwn[8];
    if (t > 0) {
#pragma unroll
      for (int nt = 0; nt < 2; ++nt)
#pragma unroll
        for (int r = 0; r < 4; ++r)
          xwn[nt * 4 + r] = base[((long)(b0 + lk * 4 + r) * Tc + (t - 1)) * 256 + n0 + nt * 16 + lr];
    }
    f32x4 acc[2];
#pragma unroll
    for (int nt = 0; nt < 2; ++nt) {
      acc[nt][0] = bf2f(xw[nt * 4 + 0]);
      acc[nt][1] = bf2f(xw[nt * 4 + 1]);
      acc[nt][2] = bf2f(xw[nt * 4 + 2]);
      acc[nt][3] = bf2f(xw[nt * 4 + 3]);
    }
#pragma unroll
    for (int kk = 0; kk < 8; ++kk) {
      short8 a = *(const short8*)&hlds[p][lr * 256 + (((kk * 4 + lk) ^ (lr & 7)) << 3)];
      acc[0] = mfma16(a, Bf[0][kk], acc[0]);
      acc[1] = mfma16(a, Bf[1][kk], acc[1]);
    }
    // relu + cvt, write new h to the other LDS buffer + global (fire-and-forget)
    u16 hv[8];
#pragma unroll
    for (int nt = 0; nt < 2; ++nt)
#pragma unroll
      for (int r = 0; r < 4; ++r) {
        int m = lk * 4 + r, j = n0 + nt * 16 + lr;
        hv[nt * 4 + r] = f2bf(fmaxf(acc[nt][r], 0.0f));
        hlds[p ^ 1][swz(m, j)] = hv[nt * 4 + r];
      }
#pragma unroll
    for (int nt = 0; nt < 2; ++nt)
#pragma unroll
      for (int r = 0; r < 4; ++r)
        base[((long)(b0 + lk * 4 + r) * Tc + t) * 256 + n0 + nt * 16 + lr] = hv[nt * 4 + r];

    asm volatile("s_waitcnt lgkmcnt(0)" ::: "memory");  // DS ops drained; vmem stays in flight
    __builtin_amdgcn_s_barrier();
    __builtin_amdgcn_sched_barrier(0);

    p ^= 1;
#pragma unroll
    for (int i = 0; i < 8; ++i) xw[i] = xwn[i];
  }
}

// ---------------- G2: q_x_mu = h_y @ Wmu^T + bmu (f32 out), q_x = mu+eps (bf16 ws) ----------------
__global__ __launch_bounds__(256) void k_g2(const u16* __restrict__ W, const u16* __restrict__ hy,
                                            const float* __restrict__ bmu, const float* __restrict__ eps_qx,
                                            float* __restrict__ out, u16* __restrict__ qx)
{
  const int k = blockIdx.y;
  const int m0 = blockIdx.x * 64 + (threadIdx.x >> 6) * 16;
  const int l = threadIdx.x & 63, lr = l & 15, lk = l >> 4;
  const u16* A = hy + ((long)k * Rc + m0 + lr) * 256 + lk * 8;
  const u16* Bw = W + OFF_YWMU + (long)k * 64 * 256;
  f32x4 acc[4];
#pragma unroll
  for (int nt = 0; nt < 4; ++nt) {
    float bv = bmu[k * 64 + nt * 16 + lr];
    acc[nt] = (f32x4){bv, bv, bv, bv};
  }
#pragma unroll
  for (int kk = 0; kk < 8; ++kk) {
    short8 a = *(const short8*)(A + kk * 32);
#pragma unroll
    for (int nt = 0; nt < 4; ++nt) {
      short8 b = *(const short8*)(Bw + (long)(nt * 16 + lr) * 256 + kk * 32 + lk * 8);
      acc[nt] = mfma16(a, b, acc[nt]);
    }
  }
#pragma unroll
  for (int nt = 0; nt < 4; ++nt)
#pragma unroll
    for (int r = 0; r < 4; ++r) {
      long idx = ((long)k * Rc + m0 + lk * 4 + r) * 64 + nt * 16 + lr;
      float v = acc[nt][r];
      out[O_QMU + idx] = v;
      qx[idx] = f2bf(v + eps_qx[idx]);
    }
}

// ---------------- G3: xW_x = q_x @ x_Wih^T + xbias -> buf2 (bf16) ----------------
__global__ __launch_bounds__(256) void k_g3(const u16* __restrict__ W, const u16* __restrict__ qx,
                                            const float* __restrict__ F, u16* __restrict__ buf2)
{
  const int k = blockIdx.y, m0 = blockIdx.x * 16;
  const int tid = threadIdx.x, wv = tid >> 6, l = tid & 63, lr = l & 15, lk = l >> 4;
  const int n0 = wv * 64;
  const u16* A = qx + ((long)k * Rc + m0 + lr) * 64 + lk * 8;
  const u16* Bw = W + OFF_XWIH + (long)k * 256 * 64;
  f32x4 acc[4];
#pragma unroll
  for (int nt = 0; nt < 4; ++nt) {
    float bv = F[FO_XB + k * 256 + n0 + nt * 16 + lr];
    acc[nt] = (f32x4){bv, bv, bv, bv};
  }
#pragma unroll
  for (int kk = 0; kk < 2; ++kk) {
    short8 a = *(const short8*)(A + kk * 32);
#pragma unroll
    for (int nt = 0; nt < 4; ++nt) {
      short8 b = *(const short8*)(Bw + (long)(n0 + nt * 16 + lr) * 64 + kk * 32 + lk * 8);
      acc[nt] = mfma16(a, b, acc[nt]);
    }
  }
  u16* outp = buf2 + (long)k * Rc * 256;
#pragma unroll
  for (int nt = 0; nt < 4; ++nt)
#pragma unroll
    for (int r = 0; r < 4; ++r)
      outp[(long)(m0 + lk * 4 + r) * 256 + n0 + nt * 16 + lr] = f2bf(acc[nt][r]);
}

// ---------------- G4: c = summary @ M2^T + cbias  (N=8, K=2048) ----------------
__global__ __launch_bounds__(256) void k_g4(const u16* __restrict__ W, const u16* __restrict__ hx,
                                            const float* __restrict__ F, float* __restrict__ cbuf)
{
  const int m0 = blockIdx.x * 64 + (threadIdx.x >> 6) * 16;
  const int l = threadIdx.x & 63, lr = l & 15, lk = l >> 4;
  const u16* M2 = W + OFF_M2;
  float bv = F[FO_CB + lr];
  f32x4 acc = (f32x4){bv, bv, bv, bv};
#pragma unroll 8
  for (int kk = 0; kk < 64; ++kk) {
    int k8 = kk >> 3, ko = kk & 7;
    short8 a = *(const short8*)(hx + ((long)k8 * Rc + m0 + lr) * 256 + ko * 32 + lk * 8);
    short8 b = *(const short8*)(M2 + (long)lr * 2048 + kk * 32 + lk * 8);
    acc = mfma16(a, b, acc);
  }
  if (lr < 8) {
#pragma unroll
    for (int r = 0; r < 4; ++r)
      cbuf[(long)(m0 + lk * 4 + r) * 8 + lr] = acc[r];
  }
}

// ---------------- S5a: z chain (one wave per batch element) ----------------
#define CASD(a, b) { float _hi = fmaxf(a, b), _lo = fminf(a, b); a = _hi; b = _lo; }
__global__ __launch_bounds__(256) void k_zchain(const float* __restrict__ F, const float* __restrict__ cbuf,
                                                const float* __restrict__ eps_z, const float* __restrict__ zq0,
                                                float* __restrict__ out, float* __restrict__ wbuf)
{
  const int wv = threadIdx.x >> 6, l = threadIdx.x & 63;
  const int b = blockIdx.x * 4 + wv;
  __shared__ float cl[4][1024];
  __shared__ float el[4][1024];
  for (int i = l; i < 1024; i += 64) cl[wv][i] = cbuf[(long)b * 1024 + i];
  for (int i = l; i < 1024; i += 64) {
    int t = i >> 3, kk = i & 7;
    el[wv][i] = eps_z[(long)t * (Bc * Kc) + b * 8 + kk];
  }
  float a2 = F[FO_A2 + l];   // A2[l>>3][l&7]
  __syncthreads();

  float z = zq0[l & 7];      // every lane holds z_prev[l&7]
  for (int t = 0; t < Tc; ++t) {
    float p = a2 * z;
    p += __shfl_xor(p, 1, 64);
    p += __shfl_xor(p, 2, 64);
    p += __shfl_xor(p, 4, 64);                  // group g=l>>3 holds sum_k1 A2[g][k1] z[k1]
    float zmu_l = __shfl(p, (l & 7) * 8, 64);   // lane l gets zmu_lin[l&7]
    float zl = zmu_l + cl[wv][t * 8 + (l & 7)]; // z_logits
    float zt = zl + el[wv][t * 8 + (l & 7)];    // z_sample

    // sparsemax over 8 values (all lanes redundantly)
    float v0 = __shfl(zt, 0, 64), v1 = __shfl(zt, 1, 64), v2 = __shfl(zt, 2, 64), v3 = __shfl(zt, 3, 64);
    float v4 = __shfl(zt, 4, 64), v5 = __shfl(zt, 5, 64), v6 = __shfl(zt, 6, 64), v7 = __shfl(zt, 7, 64);
    CASD(v0, v1); CASD(v2, v3); CASD(v4, v5); CASD(v6, v7);
    CASD(v0, v2); CASD(v1, v3); CASD(v4, v6); CASD(v5, v7);
    CASD(v1, v2); CASD(v5, v6);
    CASD(v0, v4); CASD(v1, v5); CASD(v2, v6); CASD(v3, v7);
    CASD(v2, v4); CASD(v3, v5);
    CASD(v1, v2); CASD(v3, v4); CASD(v5, v6);   // v0 >= v1 >= ... >= v7
    float s0 = v0, s1 = s0 + v1, s2 = s1 + v2, s3 = s2 + v3;
    float s4 = s3 + v4, s5 = s4 + v5, s6 = s5 + v6, s7 = s6 + v7;
    int kz = 1;
    kz += (2.0f * v1 > s1 - 1.0f) ? 1 : 0;
    kz += (3.0f * v2 > s2 - 1.0f) ? 1 : 0;
    kz += (4.0f * v3 > s3 - 1.0f) ? 1 : 0;
    kz += (5.0f * v4 > s4 - 1.0f) ? 1 : 0;
    kz += (6.0f * v5 > s5 - 1.0f) ? 1 : 0;
    kz += (7.0f * v6 > s6 - 1.0f) ? 1 : 0;
    kz += (8.0f * v7 > s7 - 1.0f) ? 1 : 0;
    float csel = s0 - 1.0f;
    csel = (kz > 1) ? s1 - 1.0f : csel;
    csel = (kz > 2) ? s2 - 1.0f : csel;
    csel = (kz > 3) ? s3 - 1.0f : csel;
    csel = (kz > 4) ? s4 - 1.0f : csel;
    csel = (kz > 5) ? s5 - 1.0f : csel;
    csel = (kz > 6) ? s6 - 1.0f : csel;
    csel = (kz > 7) ? s7 - 1.0f : csel;
    float tau = csel / (float)kz;
    float wk = fmaxf(zt - tau, 0.0f);

    if (l < 8) {
      long r = (long)b * Tc + t;
      out[O_ZL + r * 8 + l] = zl;
      out[O_ZS + r * 8 + l] = zt;
      wbuf[r * 8 + l] = wk;
    }
    z = zt;
  }
}

// ---------------- S5b: x_sample = sum_k w * mu + eps_x ----------------
__global__ void k_xsample(const float* __restrict__ wbuf, const float* __restrict__ eps_x,
                          float* __restrict__ out)
{
  long idx = (long)blockIdx.x * 256 + threadIdx.x;
  if (idx >= (long)Rc * Xc) return;
  long r = idx >> 6;          // b*T + t
  int x = (int)(idx & 63);
  long b = r >> 7;
  long t = r & 127;
  float s = eps_x[(t * Bc + b) * 64 + x];
#pragma unroll
  for (int k = 0; k < 8; ++k)
    s += wbuf[r * 8 + k] * out[O_QMU + ((long)k * Rc + r) * 64 + x];
  out[O_XS + idx] = s;
}

// ---------------- launch ----------------
extern "C" void kernel_launch(void* const* d_in, const int* in_sizes, int n_in,
                              void* d_out, int out_size, void* d_ws, size_t ws_size,
                              hipStream_t stream) {
  (void)in_sizes; (void)n_in; (void)out_size; (void)ws_size;
  const float* data   = (const float*)d_in[0];
  const float* eps_qx = (const float*)d_in[1];
  const float* eps_z  = (const float*)d_in[2];
  const float* eps_x  = (const float*)d_in[3];
  const float* yWih   = (const float*)d_in[4];
  const float* yWhh   = (const float*)d_in[5];
  const float* ybih   = (const float*)d_in[6];
  const float* ybhh   = (const float*)d_in[7];
  const float* yh0    = (const float*)d_in[8];
  const float* yWmu   = (const float*)d_in[9];
  const float* ybmu   = (const float*)d_in[10];
  const float* xWih   = (const float*)d_in[11];
  const float* xWhh   = (const float*)d_in[12];
  const float* xbih   = (const float*)d_in[13];
  const float* xbhh   = (const float*)d_in[14];
  const float* xh0    = (const float*)d_in[15];
  const float* dsW    = (const float*)d_in[16];
  const float* dsb    = (const float*)d_in[17];
  const float* cbW1   = (const float*)d_in[18];
  const float* cbb1   = (const float*)d_in[19];
  const float* cbW2   = (const float*)d_in[20];
  const float* cbb2   = (const float*)d_in[21];
  const float* zq0    = (const float*)d_in[22];

  u16*   W = (u16*)d_ws;
  float* F = (float*)((char*)d_ws + U16_BYTES);
  float* out = (float*)d_out;

  hipLaunchKernelGGL(k_prep, dim3(1024), dim3(256), 0, stream,
                     data, yWih, yWhh, yWmu, xWih, xWhh, ybih, ybhh, xbih, xbhh, W, F, out);
  hipLaunchKernelGGL(k_prep2, dim3(129), dim3(256), 0, stream,
                     dsW, dsb, cbW1, cbb1, cbW2, cbb2, W, F);
  hipLaunchKernelGGL(k_g1, dim3(512, 8), dim3(256), 0, stream, W, F, W + OFF_BUF1);
  hipLaunchKernelGGL(k_rnn, dim3(4, 8), dim3(512), 0, stream, W + OFF_BUF1, W + OFF_YWHH, yh0);
  hipLaunchKernelGGL(k_g2, dim3(128, 8), dim3(256), 0, stream,
                     W, W + OFF_BUF1, ybmu, eps_qx, out, W + OFF_QX);
  hipLaunchKernelGGL(k_g3, dim3(512, 8), dim3(256), 0, stream, W, W + OFF_QX, F, W + OFF_BUF2);
  hipLaunchKernelGGL(k_rnn, dim3(4, 8), dim3(512), 0, stream, W + OFF_BUF2, W + OFF_XWHH, xh0);
  hipLaunchKernelGGL(k_g4, dim3(128), dim3(256), 0, stream, W, W + OFF_BUF2, F, F + FO_C);
  hipLaunchKernelGGL(k_zchain, dim3(16), dim3(256), 0, stream, F, F + FO_C, eps_z, zq0, out, F + FO_W);
  hipLaunchKernelGGL(k_xsample, dim3(2048), dim3(256), 0, stream, F + FO_W, eps_x, out);
}

// Round 3
// 388.885 us; speedup vs baseline: 1.3704x; 1.3397x over previous
//
#include <hip/hip_runtime.h>

// ---------------- problem constants ----------------
#define Kc 8
#define Bc 64
#define Tc 128
#define Yc 128
#define Xc 64
#define Hc 256
#define Rc 8192   // B*T

typedef unsigned short u16;
typedef unsigned int u32;
typedef __attribute__((ext_vector_type(8))) short short8;  // 8 bf16 (4 VGPR)
typedef __attribute__((ext_vector_type(4))) float f32x4;   // MFMA C/D
typedef __attribute__((ext_vector_type(2))) unsigned int u32x2;

// ---------------- ws layout (u16 element offsets) ----------------
#define OFF_DATA 0L         // data bf16        [8192][128] row-major
#define OFF_YWIH 1048576L   // y_Wih bf16       [8][256][128] row-major
#define OFF_YWHH 1310720L   // y_Whh bf16       [8][256][256] row-major
#define OFF_YWMU 1835008L   // y_Wmu bf16       [8][64][256] row-major
#define OFF_XWIH 1966080L   // x_Wih bf16       [8][256][64] row-major
#define OFF_XWHH 2097152L   // x_Whh bf16       [8][256][256] row-major
#define OFF_M2   2621440L   // M2 = W2@dsW bf16 [16(pad)][2048] row-major
#define OFF_QX   2654208L   // q_x bf16         [8][8192][64] row-major
#define OFF_BUF1 6848512L   // xW_y -> h_y bf16 frag-major tiles [8][4][128][4096]
#define OFF_BUF2 23625728L  // xW_x -> h_x bf16 frag-major tiles [8][4][128][4096]
#define U16_BYTES 80805888L
// f32 region (after u16 region)
#define FO_YB 0L      // y bias (bih+bhh) [8][256]
#define FO_XB 2048L   // x bias           [8][256]
#define FO_CB 4096L   // combiner const   [16]
#define FO_A2 4112L   // A2 = W2@W1       [8][8]
#define FO_C  8192L   // c buffer         [8192][8]
#define FO_W  73728L  // sparsemax w      [8192][8]

// frag-major tile (16 batch m x 256 hidden n, 4096 u16):
//   u16 idx(m,n) = (n>>5)*512 + ((n>>3)&3)*128 + m*8 + (n&7)
// A-frag & B-frag read (lane l, kk): idx = kk*512 + (l>>4)*128 + (l&15)*8  (16B contiguous)
// D write (lane l, nt):  n = wv*64+nt*16+lk*4+r ->
//   roff = (wv*2+(nt>>1))*512 + ((nt&1)*2+(lk>>1))*128 + lr*8 + (lk&1)*4   (4 u16 run)

// ---------------- output layout (f32 elements) ----------------
#define O_XS  0L        // x_sample   [64][128][64]
#define O_QMU 524288L   // q_x_mu     [8][64][128][64]
#define O_QLV 4718592L  // q_x_logvar [8][64][128][64] (zeros)
#define O_ZS  8912896L  // z_sample   [64][128][8]
#define O_ZL  8978432L  // z_logits   [64][128][8]

// ---------------- helpers ----------------
__device__ __forceinline__ u16 f2bf(float f) {
  union { float f; u32 u; } v; v.f = f;
  u32 u = v.u;
  return (u16)((u + 0x7FFFu + ((u >> 16) & 1u)) >> 16);  // RNE
}
__device__ __forceinline__ float bitsf(u32 u) {
  union { u32 u; float f; } v; v.u = u; return v.f;
}
__device__ __forceinline__ u32 cvt_pk(float lo, float hi) {
  u32 r;
  asm("v_cvt_pk_bf16_f32 %0, %1, %2" : "=v"(r) : "v"(lo), "v"(hi));
  return r;
}
__device__ __forceinline__ f32x4 mfma16(short8 a, short8 b, f32x4 c) {
  return __builtin_amdgcn_mfma_f32_16x16x32_bf16(a, b, c, 0, 0, 0);
}

// ---------------- P1: dtype conversions, biases, zero logvar ----------------
__global__ void k_prep(const float* __restrict__ data, const float* __restrict__ yWih,
                       const float* __restrict__ yWhh, const float* __restrict__ yWmu,
                       const float* __restrict__ xWih, const float* __restrict__ xWhh,
                       const float* __restrict__ ybih, const float* __restrict__ ybhh,
                       const float* __restrict__ xbih, const float* __restrict__ xbhh,
                       u16* __restrict__ W, float* __restrict__ F, float* __restrict__ out)
{
  long tid = (long)blockIdx.x * blockDim.x + threadIdx.x;
  long stride = (long)gridDim.x * blockDim.x;
  for (long i = tid; i < 1048576L; i += stride) W[OFF_DATA + i] = f2bf(data[i]);
  for (long i = tid; i < 262144L;  i += stride) W[OFF_YWIH + i] = f2bf(yWih[i]);
  for (long i = tid; i < 524288L;  i += stride) W[OFF_YWHH + i] = f2bf(yWhh[i]);
  for (long i = tid; i < 131072L;  i += stride) W[OFF_YWMU + i] = f2bf(yWmu[i]);
  for (long i = tid; i < 131072L;  i += stride) W[OFF_XWIH + i] = f2bf(xWih[i]);
  for (long i = tid; i < 524288L;  i += stride) W[OFF_XWHH + i] = f2bf(xWhh[i]);
  for (long i = tid; i < 2048L;    i += stride) F[FO_YB + i] = ybih[i] + ybhh[i];
  for (long i = tid; i < 2048L;    i += stride) F[FO_XB + i] = xbih[i] + xbhh[i];
  for (long i = tid; i < 4194304L; i += stride) out[O_QLV + i] = 0.0f;
}

// ---------------- P2: combiner collapse  M2 = W2@dsW,  A2 = W2@W1,  cbias ----------------
__global__ void k_prep2(const float* __restrict__ dsW, const float* __restrict__ dsb,
                        const float* __restrict__ W1, const float* __restrict__ b1,
                        const float* __restrict__ W2, const float* __restrict__ b2,
                        u16* __restrict__ W, float* __restrict__ F)
{
  if (blockIdx.x < 128) {  // M2 [16][2048] (rows >=8 zero-padded)
    long i = (long)blockIdx.x * 256 + threadIdx.x;   // 0..32767
    int k2 = (int)(i >> 11), ki = (int)(i & 2047);
    float s = 0.0f;
    if (k2 < 8) {
      for (int j = 0; j < 256; ++j) s += W2[k2 * 256 + j] * dsW[(long)j * 2048 + ki];
    }
    W[OFF_M2 + i] = f2bf(s);
  } else {  // blockIdx.x == 128
    int t = threadIdx.x;
    if (t < 64) {            // A2[k2][k1] = sum_j W2[k2,j] W1[j,k1]
      int k2 = t >> 3, k1 = t & 7;
      float s = 0.0f;
      for (int j = 0; j < 256; ++j) s += W2[k2 * 256 + j] * W1[j * 8 + k1];
      F[FO_A2 + t] = s;
    } else if (t < 80) {     // cbias[k2] = W2@(dsb+b1) + b2   (pad to 16)
      int k2 = t - 64;
      float s = 0.0f;
      if (k2 < 8) {
        for (int j = 0; j < 256; ++j) s += W2[k2 * 256 + j] * (dsb[j] + b1[j]);
        s += b2[k2];
      }
      F[FO_CB + k2] = s;
    }
  }
}

// ---------------- G1: xW_y = y_Wih(A) x data(B) + ybias -> buf1 frag-major ----------------
// grid (4 bsplit * 32 tchunk, 8 k), 256 thr (4 waves = 4 n-stripes of 64), 4 t per block
__global__ __launch_bounds__(256) void k_g1(const u16* __restrict__ W, const float* __restrict__ F,
                                            u16* __restrict__ buf)
{
  const int k = blockIdx.y, bs = blockIdx.x >> 5, t0 = (blockIdx.x & 31) * 4;
  const int tid = threadIdx.x, wv = tid >> 6, l = tid & 63, lr = l & 15, lk = l >> 4;
  const int b0 = bs * 16;
  short8 Af[4][4];
  const u16* Ak = W + OFF_YWIH + (long)k * 32768;
#pragma unroll
  for (int nt = 0; nt < 4; ++nt)
#pragma unroll
    for (int kk = 0; kk < 4; ++kk)
      Af[nt][kk] = *(const short8*)(Ak + (long)(wv * 64 + nt * 16 + lr) * 128 + kk * 32 + lk * 8);
  f32x4 bias[4];
#pragma unroll
  for (int nt = 0; nt < 4; ++nt)
    bias[nt] = *(const f32x4*)&F[FO_YB + k * 256 + wv * 64 + nt * 16 + lk * 4];
  int roff[4];
#pragma unroll
  for (int nt = 0; nt < 4; ++nt)
    roff[nt] = (wv * 2 + (nt >> 1)) * 512 + ((nt & 1) * 2 + (lk >> 1)) * 128 + lr * 8 + (lk & 1) * 4;

  for (int ti = 0; ti < 4; ++ti) {
    int t = t0 + ti;
    f32x4 acc[4] = {bias[0], bias[1], bias[2], bias[3]};
    const u16* Brow = W + OFF_DATA + ((long)(b0 + lr) * 128 + t) * 128 + lk * 8;
#pragma unroll
    for (int kk = 0; kk < 4; ++kk) {
      short8 b = *(const short8*)(Brow + kk * 32);
      acc[0] = mfma16(Af[0][kk], b, acc[0]);
      acc[1] = mfma16(Af[1][kk], b, acc[1]);
      acc[2] = mfma16(Af[2][kk], b, acc[2]);
      acc[3] = mfma16(Af[3][kk], b, acc[3]);
    }
    u16* tb = buf + ((long)(k * 4 + bs) * 128 + t) * 4096;
#pragma unroll
    for (int nt = 0; nt < 4; ++nt) {
      u32 d0 = cvt_pk(acc[nt][0], acc[nt][1]);
      u32 d1 = cvt_pk(acc[nt][2], acc[nt][3]);
      *(u32x2*)(tb + roff[nt]) = (u32x2){d0, d1};
    }
  }
}

// ---------------- R: backward ReLU RNN (shared y/x). In-place xW -> h, frag-major ----------------
// grid (4 bsplit, 8 k), 256 thr (4 waves x 64-n stripes). Whh frags resident (128 VGPR).
__global__ __launch_bounds__(256, 1) void k_rnn(u16* __restrict__ buf,
                                                const u16* __restrict__ Whh,
                                                const float* __restrict__ h0)
{
  const int k = blockIdx.y, bs = blockIdx.x;
  const int tid = threadIdx.x, wv = tid >> 6, l = tid & 63, lr = l & 15, lk = l >> 4;
  __shared__ __align__(16) u16 hlds[2][4096];

  short8 Bf[4][8];
  const u16* Wk = Whh + (long)k * 65536;
#pragma unroll
  for (int nt = 0; nt < 4; ++nt)
#pragma unroll
    for (int kk = 0; kk < 8; ++kk)
      Bf[nt][kk] = *(const short8*)(Wk + (long)(wv * 64 + nt * 16 + lr) * 256 + kk * 32 + lk * 8);

  // h0 init into hlds[0] (frag-major)
  for (int i = tid; i < 4096; i += 256) {
    int n = (i >> 9) * 32 + ((i >> 7) & 3) * 8 + (i & 7);
    hlds[0][i] = f2bf(h0[k * 256 + n]);
  }

  u16* tb0 = buf + ((long)(k * 4 + bs) * 128) * 4096;  // tile(t) = tb0 + t*4096
  int roff[4];
#pragma unroll
  for (int nt = 0; nt < 4; ++nt)
    roff[nt] = (wv * 2 + (nt >> 1)) * 512 + ((nt & 1) * 2 + (lk >> 1)) * 128 + lr * 8 + (lk & 1) * 4;

  // preload xw(Tc-1)
  u32 xw[8];
#pragma unroll
  for (int nt = 0; nt < 4; ++nt) {
    u32x2 v = *(const u32x2*)(tb0 + (long)(Tc - 1) * 4096 + roff[nt]);
    xw[nt * 2 + 0] = v.x; xw[nt * 2 + 1] = v.y;
  }
  __syncthreads();

  int p = 0;
  for (int t = Tc - 1; t >= 0; --t) {
    // prefetch xw(t-1)
    u32 pf[8];
    if (t > 0) {
#pragma unroll
      for (int nt = 0; nt < 4; ++nt) {
        u32x2 v = *(const u32x2*)(tb0 + (long)(t - 1) * 4096 + roff[nt]);
        pf[nt * 2 + 0] = v.x; pf[nt * 2 + 1] = v.y;
      }
    }
    // acc init from xw(t) (bf16 pairs -> f32)
    f32x4 acc[4];
#pragma unroll
    for (int nt = 0; nt < 4; ++nt) {
      u32 w0 = xw[nt * 2], w1 = xw[nt * 2 + 1];
      acc[nt][0] = bitsf(w0 << 16);
      acc[nt][1] = bitsf(w0 & 0xffff0000u);
      acc[nt][2] = bitsf(w1 << 16);
      acc[nt][3] = bitsf(w1 & 0xffff0000u);
    }
    // MFMA over K=256 (8 kk), shared B-frags from LDS (contiguous, conflict-free)
#pragma unroll
    for (int kk = 0; kk < 8; ++kk) {
      short8 b = *(const short8*)&hlds[p][kk * 512 + lk * 128 + lr * 8];
      acc[0] = mfma16(Bf[0][kk], b, acc[0]);
      acc[1] = mfma16(Bf[1][kk], b, acc[1]);
      acc[2] = mfma16(Bf[2][kk], b, acc[2]);
      acc[3] = mfma16(Bf[3][kk], b, acc[3]);
    }
    // relu + pack; write h(t) to LDS (next step) and global (fire-and-forget)
    u16* tb = tb0 + (long)t * 4096;
#pragma unroll
    for (int nt = 0; nt < 4; ++nt) {
      float f0 = fmaxf(acc[nt][0], 0.0f), f1 = fmaxf(acc[nt][1], 0.0f);
      float f2 = fmaxf(acc[nt][2], 0.0f), f3 = fmaxf(acc[nt][3], 0.0f);
      u32x2 d = (u32x2){cvt_pk(f0, f1), cvt_pk(f2, f3)};
      *(u32x2*)&hlds[p ^ 1][roff[nt]] = d;
      *(u32x2*)(tb + roff[nt]) = d;
    }
    asm volatile("s_waitcnt lgkmcnt(0)" ::: "memory");  // DS drained; vmem stays in flight
    __builtin_amdgcn_s_barrier();
    __builtin_amdgcn_sched_barrier(0);
    p ^= 1;
#pragma unroll
    for (int i = 0; i < 8; ++i) xw[i] = pf[i];
  }
}

// ---------------- G2: q_x_mu = Wmu(A) x h_y(B) + bmu ; qx = mu + eps (bf16) ----------------
// grid (4 bsplit * 32 tchunk, 8 k), 4 waves = 4 x-stripes of 16, 4 t per block
__global__ __launch_bounds__(256) void k_g2(const u16* __restrict__ W, const u16* __restrict__ hy,
                                            const float* __restrict__ bmu, const float* __restrict__ eps,
                                            float* __restrict__ out, u16* __restrict__ qx)
{
  const int k = blockIdx.y, bs = blockIdx.x >> 5, t0 = (blockIdx.x & 31) * 4;
  const int tid = threadIdx.x, wv = tid >> 6, l = tid & 63, lr = l & 15, lk = l >> 4;
  const int b0 = bs * 16, x0 = wv * 16;
  short8 Af[8];
  const u16* Ak = W + OFF_YWMU + (long)k * 16384;
#pragma unroll
  for (int kk = 0; kk < 8; ++kk)
    Af[kk] = *(const short8*)(Ak + (long)(x0 + lr) * 256 + kk * 32 + lk * 8);
  f32x4 bias = *(const f32x4*)&bmu[k * 64 + x0 + lk * 4];

  for (int ti = 0; ti < 4; ++ti) {
    int t = t0 + ti;
    const u16* tb = hy + ((long)(k * 4 + bs) * 128 + t) * 4096 + lk * 128 + lr * 8;
    f32x4 a0 = bias, a1 = (f32x4){0.f, 0.f, 0.f, 0.f};
#pragma unroll
    for (int kk = 0; kk < 8; kk += 2) {
      short8 bA = *(const short8*)(tb + kk * 512);
      short8 bB = *(const short8*)(tb + (kk + 1) * 512);
      a0 = mfma16(Af[kk], bA, a0);
      a1 = mfma16(Af[kk + 1], bB, a1);
    }
    f32x4 mu = a0 + a1;
    long idx = ((long)k * Rc + (b0 + lr) * 128 + t) * 64 + x0 + lk * 4;
    *(f32x4*)&out[O_QMU + idx] = mu;
    f32x4 e = *(const f32x4*)&eps[idx];
    f32x4 q = mu + e;
    *(u32x2*)(qx + idx) = (u32x2){cvt_pk(q[0], q[1]), cvt_pk(q[2], q[3])};
  }
}

// ---------------- G3: xW_x = x_Wih(A) x q_x(B) + xbias -> buf2 frag-major ----------------
__global__ __launch_bounds__(256) void k_g3(const u16* __restrict__ W, const u16* __restrict__ qx,
                                            const float* __restrict__ F, u16* __restrict__ buf)
{
  const int k = blockIdx.y, bs = blockIdx.x >> 5, t0 = (blockIdx.x & 31) * 4;
  const int tid = threadIdx.x, wv = tid >> 6, l = tid & 63, lr = l & 15, lk = l >> 4;
  const int b0 = bs * 16;
  short8 Af[4][2];
  const u16* Ak = W + OFF_XWIH + (long)k * 16384;
#pragma unroll
  for (int nt = 0; nt < 4; ++nt)
#pragma unroll
    for (int kk = 0; kk < 2; ++kk)
      Af[nt][kk] = *(const short8*)(Ak + (long)(wv * 64 + nt * 16 + lr) * 64 + kk * 32 + lk * 8);
  f32x4 bias[4];
#pragma unroll
  for (int nt = 0; nt < 4; ++nt)
    bias[nt] = *(const f32x4*)&F[FO_XB + k * 256 + wv * 64 + nt * 16 + lk * 4];
  int roff[4];
#pragma unroll
  for (int nt = 0; nt < 4; ++nt)
    roff[nt] = (wv * 2 + (nt >> 1)) * 512 + ((nt & 1) * 2 + (lk >> 1)) * 128 + lr * 8 + (lk & 1) * 4;

  for (int ti = 0; ti < 4; ++ti) {
    int t = t0 + ti;
    f32x4 acc[4] = {bias[0], bias[1], bias[2], bias[3]};
    const u16* Brow = qx + ((long)k * Rc + (b0 + lr) * 128 + t) * 64 + lk * 8;
#pragma unroll
    for (int kk = 0; kk < 2; ++kk) {
      short8 b = *(const short8*)(Brow + kk * 32);
      acc[0] = mfma16(Af[0][kk], b, acc[0]);
      acc[1] = mfma16(Af[1][kk], b, acc[1]);
      acc[2] = mfma16(Af[2][kk], b, acc[2]);
      acc[3] = mfma16(Af[3][kk], b, acc[3]);
    }
    u16* tb = buf + ((long)(k * 4 + bs) * 128 + t) * 4096;
#pragma unroll
    for (int nt = 0; nt < 4; ++nt) {
      u32 d0 = cvt_pk(acc[nt][0], acc[nt][1]);
      u32 d1 = cvt_pk(acc[nt][2], acc[nt][3]);
      *(u32x2*)(tb + roff[nt]) = (u32x2){d0, d1};
    }
  }
}

// ---------------- G4: c = h_x(A) x M2(B) + cbias  (D: rows=batch, cols=k2) ----------------
// grid (128), 4 waves, each wave one (bsplit,t) tile; K = 8k x 256
__global__ __launch_bounds__(256) void k_g4(const u16* __restrict__ W, const u16* __restrict__ hx,
                                            const float* __restrict__ F, float* __restrict__ cbuf)
{
  const int tid = threadIdx.x, wv = tid >> 6, l = tid & 63, lr = l & 15, lk = l >> 4;
  const int tile = blockIdx.x * 4 + wv, bs = tile >> 7, t = tile & 127, b0 = bs * 16;
  const u16* M2 = W + OFF_M2 + lr * 2048 + lk * 8;
  float bv = F[FO_CB + lr];
  f32x4 acc[4];
  acc[0] = (f32x4){bv, bv, bv, bv};
  acc[1] = acc[2] = acc[3] = (f32x4){0.f, 0.f, 0.f, 0.f};
#pragma unroll
  for (int k8 = 0; k8 < 8; ++k8) {
    const u16* tb = hx + ((long)(k8 * 4 + bs) * 128 + t) * 4096 + lk * 128 + lr * 8;
    const u16* m2 = M2 + k8 * 256;
#pragma unroll
    for (int kk = 0; kk < 8; ++kk) {
      short8 a = *(const short8*)(tb + kk * 512);
      short8 b = *(const short8*)(m2 + kk * 32);
      acc[kk & 3] = mfma16(a, b, acc[kk & 3]);
    }
  }
  f32x4 s = acc[0] + acc[1] + acc[2] + acc[3];
  if (lr < 8) {
#pragma unroll
    for (int r = 0; r < 4; ++r)
      cbuf[((long)(b0 + lk * 4 + r) * 128 + t) * 8 + lr] = s[r];
  }
}

// ---------------- S5a: z chain (one wave per batch element) ----------------
#define CASD(a, b) { float _hi = fmaxf(a, b), _lo = fminf(a, b); a = _hi; b = _lo; }
__global__ __launch_bounds__(256) void k_zchain(const float* __restrict__ F, const float* __restrict__ cbuf,
                                                const float* __restrict__ eps_z, const float* __restrict__ zq0,
                                                float* __restrict__ out, float* __restrict__ wbuf)
{
  const int wv = threadIdx.x >> 6, l = threadIdx.x & 63;
  const int b = blockIdx.x * 4 + wv;
  __shared__ float cl[4][1024];
  __shared__ float el[4][1024];
  for (int i = l; i < 1024; i += 64) cl[wv][i] = cbuf[(long)b * 1024 + i];
  for (int i = l; i < 1024; i += 64) {
    int t = i >> 3, kk = i & 7;
    el[wv][i] = eps_z[(long)t * (Bc * Kc) + b * 8 + kk];
  }
  float a2 = F[FO_A2 + l];   // A2[l>>3][l&7]
  __syncthreads();

  float z = zq0[l & 7];      // every lane holds z_prev[l&7]
  for (int t = 0; t < Tc; ++t) {
    float p = a2 * z;
    p += __shfl_xor(p, 1, 64);
    p += __shfl_xor(p, 2, 64);
    p += __shfl_xor(p, 4, 64);                  // group g=l>>3 holds sum_k1 A2[g][k1] z[k1]
    float zmu_l = __shfl(p, (l & 7) * 8, 64);   // lane l gets zmu_lin[l&7]
    float zl = zmu_l + cl[wv][t * 8 + (l & 7)]; // z_logits
    float zt = zl + el[wv][t * 8 + (l & 7)];    // z_sample

    // sparsemax over 8 values (all lanes redundantly)
    float v0 = __shfl(zt, 0, 64), v1 = __shfl(zt, 1, 64), v2 = __shfl(zt, 2, 64), v3 = __shfl(zt, 3, 64);
    float v4 = __shfl(zt, 4, 64), v5 = __shfl(zt, 5, 64), v6 = __shfl(zt, 6, 64), v7 = __shfl(zt, 7, 64);
    CASD(v0, v1); CASD(v2, v3); CASD(v4, v5); CASD(v6, v7);
    CASD(v0, v2); CASD(v1, v3); CASD(v4, v6); CASD(v5, v7);
    CASD(v1, v2); CASD(v5, v6);
    CASD(v0, v4); CASD(v1, v5); CASD(v2, v6); CASD(v3, v7);
    CASD(v2, v4); CASD(v3, v5);
    CASD(v1, v2); CASD(v3, v4); CASD(v5, v6);   // v0 >= v1 >= ... >= v7
    float s0 = v0, s1 = s0 + v1, s2 = s1 + v2, s3 = s2 + v3;
    float s4 = s3 + v4, s5 = s4 + v5, s6 = s5 + v6, s7 = s6 + v7;
    int kz = 1;
    kz += (2.0f * v1 > s1 - 1.0f) ? 1 : 0;
    kz += (3.0f * v2 > s2 - 1.0f) ? 1 : 0;
    kz += (4.0f * v3 > s3 - 1.0f) ? 1 : 0;
    kz += (5.0f * v4 > s4 - 1.0f) ? 1 : 0;
    kz += (6.0f * v5 > s5 - 1.0f) ? 1 : 0;
    kz += (7.0f * v6 > s6 - 1.0f) ? 1 : 0;
    kz += (8.0f * v7 > s7 - 1.0f) ? 1 : 0;
    float csel = s0 - 1.0f;
    csel = (kz > 1) ? s1 - 1.0f : csel;
    csel = (kz > 2) ? s2 - 1.0f : csel;
    csel = (kz > 3) ? s3 - 1.0f : csel;
    csel = (kz > 4) ? s4 - 1.0f : csel;
    csel = (kz > 5) ? s5 - 1.0f : csel;
    csel = (kz > 6) ? s6 - 1.0f : csel;
    csel = (kz > 7) ? s7 - 1.0f : csel;
    float tau = csel / (float)kz;
    float wk = fmaxf(zt - tau, 0.0f);

    if (l < 8) {
      long r = (long)b * Tc + t;
      out[O_ZL + r * 8 + l] = zl;
      out[O_ZS + r * 8 + l] = zt;
      wbuf[r * 8 + l] = wk;
    }
    z = zt;
  }
}

// ---------------- S5b: x_sample = sum_k w * mu + eps_x ----------------
__global__ void k_xsample(const float* __restrict__ wbuf, const float* __restrict__ eps_x,
                          float* __restrict__ out)
{
  long idx = (long)blockIdx.x * 256 + threadIdx.x;
  if (idx >= (long)Rc * Xc) return;
  long r = idx >> 6;          // b*T + t
  int x = (int)(idx & 63);
  long b = r >> 7;
  long t = r & 127;
  float s = eps_x[(t * Bc + b) * 64 + x];
#pragma unroll
  for (int k = 0; k < 8; ++k)
    s += wbuf[r * 8 + k] * out[O_QMU + ((long)k * Rc + r) * 64 + x];
  out[O_XS + idx] = s;
}

// ---------------- launch ----------------
extern "C" void kernel_launch(void* const* d_in, const int* in_sizes, int n_in,
                              void* d_out, int out_size, void* d_ws, size_t ws_size,
                              hipStream_t stream) {
  (void)in_sizes; (void)n_in; (void)out_size; (void)ws_size;
  const float* data   = (const float*)d_in[0];
  const float* eps_qx = (const float*)d_in[1];
  const float* eps_z  = (const float*)d_in[2];
  const float* eps_x  = (const float*)d_in[3];
  const float* yWih   = (const float*)d_in[4];
  const float* yWhh   = (const float*)d_in[5];
  const float* ybih   = (const float*)d_in[6];
  const float* ybhh   = (const float*)d_in[7];
  const float* yh0    = (const float*)d_in[8];
  const float* yWmu   = (const float*)d_in[9];
  const float* ybmu   = (const float*)d_in[10];
  const float* xWih   = (const float*)d_in[11];
  const float* xWhh   = (const float*)d_in[12];
  const float* xbih   = (const float*)d_in[13];
  const float* xbhh   = (const float*)d_in[14];
  const float* xh0    = (const float*)d_in[15];
  const float* dsW    = (const float*)d_in[16];
  const float* dsb    = (const float*)d_in[17];
  const float* cbW1   = (const float*)d_in[18];
  const float* cbb1   = (const float*)d_in[19];
  const float* cbW2   = (const float*)d_in[20];
  const float* cbb2   = (const float*)d_in[21];
  const float* zq0    = (const float*)d_in[22];

  u16*   W = (u16*)d_ws;
  float* F = (float*)((char*)d_ws + U16_BYTES);
  float* out = (float*)d_out;

  hipLaunchKernelGGL(k_prep, dim3(1024), dim3(256), 0, stream,
                     data, yWih, yWhh, yWmu, xWih, xWhh, ybih, ybhh, xbih, xbhh, W, F, out);
  hipLaunchKernelGGL(k_prep2, dim3(129), dim3(256), 0, stream,
                     dsW, dsb, cbW1, cbb1, cbW2, cbb2, W, F);
  hipLaunchKernelGGL(k_g1, dim3(128, 8), dim3(256), 0, stream, W, F, W + OFF_BUF1);
  hipLaunchKernelGGL(k_rnn, dim3(4, 8), dim3(256), 0, stream, W + OFF_BUF1, W + OFF_YWHH, yh0);
  hipLaunchKernelGGL(k_g2, dim3(128, 8), dim3(256), 0, stream,
                     W, W + OFF_BUF1, ybmu, eps_qx, out, W + OFF_QX);
  hipLaunchKernelGGL(k_g3, dim3(128, 8), dim3(256), 0, stream, W, W + OFF_QX, F, W + OFF_BUF2);
  hipLaunchKernelGGL(k_rnn, dim3(4, 8), dim3(256), 0, stream, W + OFF_BUF2, W + OFF_XWHH, xh0);
  hipLaunchKernelGGL(k_g4, dim3(128), dim3(256), 0, stream, W, W + OFF_BUF2, F, F + FO_C);
  hipLaunchKernelGGL(k_zchain, dim3(16), dim3(256), 0, stream, F, F + FO_C, eps_z, zq0, out, F + FO_W);
  hipLaunchKernelGGL(k_xsample, dim3(2048), dim3(256), 0, stream, F + FO_W, eps_x, out);
}

// Round 4
// 388.169 us; speedup vs baseline: 1.3729x; 1.0018x over previous
//
#include <hip/hip_runtime.h>

// ---------------- problem constants ----------------
#define Kc 8
#define Bc 64
#define Tc 128
#define Yc 128
#define Xc 64
#define Hc 256
#define Rc 8192   // B*T

typedef unsigned short u16;
typedef unsigned int u32;
typedef __attribute__((ext_vector_type(8))) short short8;  // 8 bf16 (4 VGPR)
typedef __attribute__((ext_vector_type(4))) float f32x4;   // MFMA C/D
typedef __attribute__((ext_vector_type(2))) unsigned int u32x2;

// ---------------- ws layout (u16 element offsets) ----------------
#define OFF_DATA 0L         // data bf16        [8192][128] row-major
#define OFF_YWIH 1048576L   // y_Wih bf16       [8][256][128] row-major
#define OFF_YWHH 1310720L   // y_Whh bf16       [8][256][256] row-major
#define OFF_YWMU 1835008L   // y_Wmu bf16       [8][64][256] row-major
#define OFF_XWIH 1966080L   // x_Wih bf16       [8][256][64] row-major
#define OFF_XWHH 2097152L   // x_Whh bf16       [8][256][256] row-major
#define OFF_M2   2621440L   // M2 = W2@dsW bf16 [16(pad)][2048] row-major
#define OFF_QX   2654208L   // q_x bf16         [8][8192][64] row-major
#define OFF_BUF1 6848512L   // xW_y -> h_y bf16 frag-major tiles [8][4][128][4096]
#define OFF_BUF2 23625728L  // xW_x -> h_x bf16 frag-major tiles [8][4][128][4096]
#define U16_BYTES 80805888L
// f32 region (after u16 region)
#define FO_YB 0L      // y bias (bih+bhh) [8][256]
#define FO_XB 2048L   // x bias           [8][256]
#define FO_CB 4096L   // combiner const   [16]
#define FO_A2 4112L   // A2 = W2@W1       [8][8]
#define FO_C  8192L   // c buffer         [8192][8]
#define FO_W  73728L  // sparsemax w      [8192][8]

// frag-major tile (16 batch m x 256 hidden n, 4096 u16):
//   u16 idx(m,n) = (n>>5)*512 + ((n>>3)&3)*128 + m*8 + (n&7)
// A-frag & B-frag read (lane l, kk): idx = kk*512 + (l>>4)*128 + (l&15)*8  (16B contiguous)
// D write (lane l, nt):  n = wv*64+nt*16+lk*4+r ->
//   roff = (wv*2+(nt>>1))*512 + ((nt&1)*2+(lk>>1))*128 + lr*8 + (lk&1)*4   (4 u16 run)

// ---------------- output layout (f32 elements) ----------------
#define O_XS  0L        // x_sample   [64][128][64]
#define O_QMU 524288L   // q_x_mu     [8][64][128][64]
#define O_QLV 4718592L  // q_x_logvar [8][64][128][64] (zeros)
#define O_ZS  8912896L  // z_sample   [64][128][8]
#define O_ZL  8978432L  // z_logits   [64][128][8]

// ---------------- helpers ----------------
__device__ __forceinline__ u16 f2bf(float f) {
  union { float f; u32 u; } v; v.f = f;
  u32 u = v.u;
  return (u16)((u + 0x7FFFu + ((u >> 16) & 1u)) >> 16);  // RNE
}
__device__ __forceinline__ float bitsf(u32 u) {
  union { u32 u; float f; } v; v.u = u; return v.f;
}
__device__ __forceinline__ u32 cvt_pk(float lo, float hi) {
  u32 r;
  asm("v_cvt_pk_bf16_f32 %0, %1, %2" : "=v"(r) : "v"(lo), "v"(hi));
  return r;
}
__device__ __forceinline__ f32x4 mfma16(short8 a, short8 b, f32x4 c) {
  return __builtin_amdgcn_mfma_f32_16x16x32_bf16(a, b, c, 0, 0, 0);
}

// ---------------- P1: dtype conversions, biases, zero logvar ----------------
__global__ void k_prep(const float* __restrict__ data, const float* __restrict__ yWih,
                       const float* __restrict__ yWhh, const float* __restrict__ yWmu,
                       const float* __restrict__ xWih, const float* __restrict__ xWhh,
                       const float* __restrict__ ybih, const float* __restrict__ ybhh,
                       const float* __restrict__ xbih, const float* __restrict__ xbhh,
                       u16* __restrict__ W, float* __restrict__ F, float* __restrict__ out)
{
  long tid = (long)blockIdx.x * blockDim.x + threadIdx.x;
  long stride = (long)gridDim.x * blockDim.x;
  for (long i = tid; i < 1048576L; i += stride) W[OFF_DATA + i] = f2bf(data[i]);
  for (long i = tid; i < 262144L;  i += stride) W[OFF_YWIH + i] = f2bf(yWih[i]);
  for (long i = tid; i < 524288L;  i += stride) W[OFF_YWHH + i] = f2bf(yWhh[i]);
  for (long i = tid; i < 131072L;  i += stride) W[OFF_YWMU + i] = f2bf(yWmu[i]);
  for (long i = tid; i < 131072L;  i += stride) W[OFF_XWIH + i] = f2bf(xWih[i]);
  for (long i = tid; i < 524288L;  i += stride) W[OFF_XWHH + i] = f2bf(xWhh[i]);
  for (long i = tid; i < 2048L;    i += stride) F[FO_YB + i] = ybih[i] + ybhh[i];
  for (long i = tid; i < 2048L;    i += stride) F[FO_XB + i] = xbih[i] + xbhh[i];
  for (long i = tid; i < 4194304L; i += stride) out[O_QLV + i] = 0.0f;
}

// ---------------- P2: combiner collapse  M2 = W2@dsW,  A2 = W2@W1,  cbias ----------------
__global__ void k_prep2(const float* __restrict__ dsW, const float* __restrict__ dsb,
                        const float* __restrict__ W1, const float* __restrict__ b1,
                        const float* __restrict__ W2, const float* __restrict__ b2,
                        u16* __restrict__ W, float* __restrict__ F)
{
  if (blockIdx.x < 128) {  // M2 [16][2048] (rows >=8 zero-padded)
    long i = (long)blockIdx.x * 256 + threadIdx.x;   // 0..32767
    int k2 = (int)(i >> 11), ki = (int)(i & 2047);
    float s = 0.0f;
    if (k2 < 8) {
      for (int j = 0; j < 256; ++j) s += W2[k2 * 256 + j] * dsW[(long)j * 2048 + ki];
    }
    W[OFF_M2 + i] = f2bf(s);
  } else {  // blockIdx.x == 128
    int t = threadIdx.x;
    if (t < 64) {            // A2[k2][k1] = sum_j W2[k2,j] W1[j,k1]
      int k2 = t >> 3, k1 = t & 7;
      float s = 0.0f;
      for (int j = 0; j < 256; ++j) s += W2[k2 * 256 + j] * W1[j * 8 + k1];
      F[FO_A2 + t] = s;
    } else if (t < 80) {     // cbias[k2] = W2@(dsb+b1) + b2   (pad to 16)
      int k2 = t - 64;
      float s = 0.0f;
      if (k2 < 8) {
        for (int j = 0; j < 256; ++j) s += W2[k2 * 256 + j] * (dsb[j] + b1[j]);
        s += b2[k2];
      }
      F[FO_CB + k2] = s;
    }
  }
}

// ---------------- G1: xW_y = y_Wih(A) x data(B) + ybias -> buf1 frag-major ----------------
// grid (4 bsplit * 32 tchunk, 8 k), 256 thr (4 waves = 4 n-stripes of 64), 4 t per block
__global__ __launch_bounds__(256) void k_g1(const u16* __restrict__ W, const float* __restrict__ F,
                                            u16* __restrict__ buf)
{
  const int k = blockIdx.y, bs = blockIdx.x >> 5, t0 = (blockIdx.x & 31) * 4;
  const int tid = threadIdx.x, wv = tid >> 6, l = tid & 63, lr = l & 15, lk = l >> 4;
  const int b0 = bs * 16;
  short8 Af[4][4];
  const u16* Ak = W + OFF_YWIH + (long)k * 32768;
#pragma unroll
  for (int nt = 0; nt < 4; ++nt)
#pragma unroll
    for (int kk = 0; kk < 4; ++kk)
      Af[nt][kk] = *(const short8*)(Ak + (long)(wv * 64 + nt * 16 + lr) * 128 + kk * 32 + lk * 8);
  f32x4 bias[4];
#pragma unroll
  for (int nt = 0; nt < 4; ++nt)
    bias[nt] = *(const f32x4*)&F[FO_YB + k * 256 + wv * 64 + nt * 16 + lk * 4];
  int roff[4];
#pragma unroll
  for (int nt = 0; nt < 4; ++nt)
    roff[nt] = (wv * 2 + (nt >> 1)) * 512 + ((nt & 1) * 2 + (lk >> 1)) * 128 + lr * 8 + (lk & 1) * 4;

  for (int ti = 0; ti < 4; ++ti) {
    int t = t0 + ti;
    f32x4 acc[4] = {bias[0], bias[1], bias[2], bias[3]};
    const u16* Brow = W + OFF_DATA + ((long)(b0 + lr) * 128 + t) * 128 + lk * 8;
#pragma unroll
    for (int kk = 0; kk < 4; ++kk) {
      short8 b = *(const short8*)(Brow + kk * 32);
      acc[0] = mfma16(Af[0][kk], b, acc[0]);
      acc[1] = mfma16(Af[1][kk], b, acc[1]);
      acc[2] = mfma16(Af[2][kk], b, acc[2]);
      acc[3] = mfma16(Af[3][kk], b, acc[3]);
    }
    u16* tb = buf + ((long)(k * 4 + bs) * 128 + t) * 4096;
#pragma unroll
    for (int nt = 0; nt < 4; ++nt) {
      u32 d0 = cvt_pk(acc[nt][0], acc[nt][1]);
      u32 d1 = cvt_pk(acc[nt][2], acc[nt][3]);
      *(u32x2*)(tb + roff[nt]) = (u32x2){d0, d1};
    }
  }
}

// ---------------- R: backward ReLU RNN (shared y/x). In-place xW -> h, frag-major ----------------
// grid (4 bsplit, 8 k), 256 thr (4 waves x 64-n stripes). Whh frags PINNED resident (128 VGPR).
__global__ __launch_bounds__(256, 1) void k_rnn(u16* __restrict__ buf,
                                                const u16* __restrict__ Whh,
                                                const float* __restrict__ h0)
{
  const int k = blockIdx.y, bs = blockIdx.x;
  const int tid = threadIdx.x, wv = tid >> 6, l = tid & 63, lr = l & 15, lk = l >> 4;
  __shared__ __align__(16) u16 hlds[2][4096];

  short8 Bf[4][8];
  const u16* Wk = Whh + (long)k * 65536;
#pragma unroll
  for (int nt = 0; nt < 4; ++nt)
#pragma unroll
    for (int kk = 0; kk < 8; ++kk)
      Bf[nt][kk] = *(const short8*)(Wk + (long)(wv * 64 + nt * 16 + lr) * 256 + kk * 32 + lk * 8);
  // PIN: make each fragment an asm-output so it cannot be rematerialized from
  // memory inside the T-loop (R2 showed VGPR=96 < 128 needed -> per-step reloads).
#pragma unroll
  for (int nt = 0; nt < 4; ++nt)
#pragma unroll
    for (int kk = 0; kk < 8; ++kk)
      asm volatile("" : "+v"(Bf[nt][kk]));

  // h0 init into hlds[0] (frag-major)
  for (int i = tid; i < 4096; i += 256) {
    int n = (i >> 9) * 32 + ((i >> 7) & 3) * 8 + (i & 7);
    hlds[0][i] = f2bf(h0[k * 256 + n]);
  }

  u16* tb0 = buf + ((long)(k * 4 + bs) * 128) * 4096;  // tile(t) = tb0 + t*4096
  int roff[4];
#pragma unroll
  for (int nt = 0; nt < 4; ++nt)
    roff[nt] = (wv * 2 + (nt >> 1)) * 512 + ((nt & 1) * 2 + (lk >> 1)) * 128 + lr * 8 + (lk & 1) * 4;

  // preload xw(Tc-1)
  u32 xw[8];
#pragma unroll
  for (int nt = 0; nt < 4; ++nt) {
    u32x2 v = *(const u32x2*)(tb0 + (long)(Tc - 1) * 4096 + roff[nt]);
    xw[nt * 2 + 0] = v.x; xw[nt * 2 + 1] = v.y;
  }
  __syncthreads();

  int p = 0;
  for (int t = Tc - 1; t >= 0; --t) {
    // prefetch xw(t-1)
    u32 pf[8];
    if (t > 0) {
#pragma unroll
      for (int nt = 0; nt < 4; ++nt) {
        u32x2 v = *(const u32x2*)(tb0 + (long)(t - 1) * 4096 + roff[nt]);
        pf[nt * 2 + 0] = v.x; pf[nt * 2 + 1] = v.y;
      }
    }
    // acc init from xw(t) (bf16 pairs -> f32)
    f32x4 acc[4];
#pragma unroll
    for (int nt = 0; nt < 4; ++nt) {
      u32 w0 = xw[nt * 2], w1 = xw[nt * 2 + 1];
      acc[nt][0] = bitsf(w0 << 16);
      acc[nt][1] = bitsf(w0 & 0xffff0000u);
      acc[nt][2] = bitsf(w1 << 16);
      acc[nt][3] = bitsf(w1 & 0xffff0000u);
    }
    // MFMA over K=256 (8 kk), shared B-frags from LDS (contiguous, conflict-free)
#pragma unroll
    for (int kk = 0; kk < 8; ++kk) {
      short8 b = *(const short8*)&hlds[p][kk * 512 + lk * 128 + lr * 8];
      acc[0] = mfma16(Bf[0][kk], b, acc[0]);
      acc[1] = mfma16(Bf[1][kk], b, acc[1]);
      acc[2] = mfma16(Bf[2][kk], b, acc[2]);
      acc[3] = mfma16(Bf[3][kk], b, acc[3]);
    }
    // relu + pack; write h(t) to LDS (next step) and global (fire-and-forget)
    u16* tb = tb0 + (long)t * 4096;
#pragma unroll
    for (int nt = 0; nt < 4; ++nt) {
      float f0 = fmaxf(acc[nt][0], 0.0f), f1 = fmaxf(acc[nt][1], 0.0f);
      float f2 = fmaxf(acc[nt][2], 0.0f), f3 = fmaxf(acc[nt][3], 0.0f);
      u32x2 d = (u32x2){cvt_pk(f0, f1), cvt_pk(f2, f3)};
      *(u32x2*)&hlds[p ^ 1][roff[nt]] = d;
      *(u32x2*)(tb + roff[nt]) = d;
    }
    asm volatile("s_waitcnt lgkmcnt(0)" ::: "memory");  // DS drained; vmem stays in flight
    __builtin_amdgcn_s_barrier();
    __builtin_amdgcn_sched_barrier(0);
    p ^= 1;
#pragma unroll
    for (int i = 0; i < 8; ++i) xw[i] = pf[i];
  }
}

// ---------------- G2: q_x_mu = Wmu(A) x h_y(B) + bmu ; qx = mu + eps (bf16) ----------------
// grid (4 bsplit * 32 tchunk, 8 k), 4 waves = 4 x-stripes of 16, 4 t per block
__global__ __launch_bounds__(256) void k_g2(const u16* __restrict__ W, const u16* __restrict__ hy,
                                            const float* __restrict__ bmu, const float* __restrict__ eps,
                                            float* __restrict__ out, u16* __restrict__ qx)
{
  const int k = blockIdx.y, bs = blockIdx.x >> 5, t0 = (blockIdx.x & 31) * 4;
  const int tid = threadIdx.x, wv = tid >> 6, l = tid & 63, lr = l & 15, lk = l >> 4;
  const int b0 = bs * 16, x0 = wv * 16;
  short8 Af[8];
  const u16* Ak = W + OFF_YWMU + (long)k * 16384;
#pragma unroll
  for (int kk = 0; kk < 8; ++kk)
    Af[kk] = *(const short8*)(Ak + (long)(x0 + lr) * 256 + kk * 32 + lk * 8);
  f32x4 bias = *(const f32x4*)&bmu[k * 64 + x0 + lk * 4];

  for (int ti = 0; ti < 4; ++ti) {
    int t = t0 + ti;
    const u16* tb = hy + ((long)(k * 4 + bs) * 128 + t) * 4096 + lk * 128 + lr * 8;
    f32x4 a0 = bias, a1 = (f32x4){0.f, 0.f, 0.f, 0.f};
#pragma unroll
    for (int kk = 0; kk < 8; kk += 2) {
      short8 bA = *(const short8*)(tb + kk * 512);
      short8 bB = *(const short8*)(tb + (kk + 1) * 512);
      a0 = mfma16(Af[kk], bA, a0);
      a1 = mfma16(Af[kk + 1], bB, a1);
    }
    f32x4 mu = a0 + a1;
    long idx = ((long)k * Rc + (b0 + lr) * 128 + t) * 64 + x0 + lk * 4;
    *(f32x4*)&out[O_QMU + idx] = mu;
    f32x4 e = *(const f32x4*)&eps[idx];
    f32x4 q = mu + e;
    *(u32x2*)(qx + idx) = (u32x2){cvt_pk(q[0], q[1]), cvt_pk(q[2], q[3])};
  }
}

// ---------------- G3: xW_x = x_Wih(A) x q_x(B) + xbias -> buf2 frag-major ----------------
__global__ __launch_bounds__(256) void k_g3(const u16* __restrict__ W, const u16* __restrict__ qx,
                                            const float* __restrict__ F, u16* __restrict__ buf)
{
  const int k = blockIdx.y, bs = blockIdx.x >> 5, t0 = (blockIdx.x & 31) * 4;
  const int tid = threadIdx.x, wv = tid >> 6, l = tid & 63, lr = l & 15, lk = l >> 4;
  const int b0 = bs * 16;
  short8 Af[4][2];
  const u16* Ak = W + OFF_XWIH + (long)k * 16384;
#pragma unroll
  for (int nt = 0; nt < 4; ++nt)
#pragma unroll
    for (int kk = 0; kk < 2; ++kk)
      Af[nt][kk] = *(const short8*)(Ak + (long)(wv * 64 + nt * 16 + lr) * 64 + kk * 32 + lk * 8);
  f32x4 bias[4];
#pragma unroll
  for (int nt = 0; nt < 4; ++nt)
    bias[nt] = *(const f32x4*)&F[FO_XB + k * 256 + wv * 64 + nt * 16 + lk * 4];
  int roff[4];
#pragma unroll
  for (int nt = 0; nt < 4; ++nt)
    roff[nt] = (wv * 2 + (nt >> 1)) * 512 + ((nt & 1) * 2 + (lk >> 1)) * 128 + lr * 8 + (lk & 1) * 4;

  for (int ti = 0; ti < 4; ++ti) {
    int t = t0 + ti;
    f32x4 acc[4] = {bias[0], bias[1], bias[2], bias[3]};
    const u16* Brow = qx + ((long)k * Rc + (b0 + lr) * 128 + t) * 64 + lk * 8;
#pragma unroll
    for (int kk = 0; kk < 2; ++kk) {
      short8 b = *(const short8*)(Brow + kk * 32);
      acc[0] = mfma16(Af[0][kk], b, acc[0]);
      acc[1] = mfma16(Af[1][kk], b, acc[1]);
      acc[2] = mfma16(Af[2][kk], b, acc[2]);
      acc[3] = mfma16(Af[3][kk], b, acc[3]);
    }
    u16* tb = buf + ((long)(k * 4 + bs) * 128 + t) * 4096;
#pragma unroll
    for (int nt = 0; nt < 4; ++nt) {
      u32 d0 = cvt_pk(acc[nt][0], acc[nt][1]);
      u32 d1 = cvt_pk(acc[nt][2], acc[nt][3]);
      *(u32x2*)(tb + roff[nt]) = (u32x2){d0, d1};
    }
  }
}

// ---------------- G4: c = h_x(A) x M2(B) + cbias  (D: rows=batch, cols=k2) ----------------
// grid (128), 4 waves, each wave one (bsplit,t) tile; K = 8k x 256
__global__ __launch_bounds__(256) void k_g4(const u16* __restrict__ W, const u16* __restrict__ hx,
                                            const float* __restrict__ F, float* __restrict__ cbuf)
{
  const int tid = threadIdx.x, wv = tid >> 6, l = tid & 63, lr = l & 15, lk = l >> 4;
  const int tile = blockIdx.x * 4 + wv, bs = tile >> 7, t = tile & 127, b0 = bs * 16;
  const u16* M2 = W + OFF_M2 + lr * 2048 + lk * 8;
  float bv = F[FO_CB + lr];
  f32x4 acc[4];
  acc[0] = (f32x4){bv, bv, bv, bv};
  acc[1] = acc[2] = acc[3] = (f32x4){0.f, 0.f, 0.f, 0.f};
#pragma unroll
  for (int k8 = 0; k8 < 8; ++k8) {
    const u16* tb = hx + ((long)(k8 * 4 + bs) * 128 + t) * 4096 + lk * 128 + lr * 8;
    const u16* m2 = M2 + k8 * 256;
#pragma unroll
    for (int kk = 0; kk < 8; ++kk) {
      short8 a = *(const short8*)(tb + kk * 512);
      short8 b = *(const short8*)(m2 + kk * 32);
      acc[kk & 3] = mfma16(a, b, acc[kk & 3]);
    }
  }
  f32x4 s = acc[0] + acc[1] + acc[2] + acc[3];
  if (lr < 8) {
#pragma unroll
    for (int r = 0; r < 4; ++r)
      cbuf[((long)(b0 + lk * 4 + r) * 128 + t) * 8 + lr] = s[r];
  }
}

// ---------------- S5a: z chain (one wave per batch element) ----------------
#define CASD(a, b) { float _hi = fmaxf(a, b), _lo = fminf(a, b); a = _hi; b = _lo; }
__global__ __launch_bounds__(256) void k_zchain(const float* __restrict__ F, const float* __restrict__ cbuf,
                                                const float* __restrict__ eps_z, const float* __restrict__ zq0,
                                                float* __restrict__ out, float* __restrict__ wbuf)
{
  const int wv = threadIdx.x >> 6, l = threadIdx.x & 63;
  const int b = blockIdx.x * 4 + wv;
  __shared__ float cl[4][1024];
  __shared__ float el[4][1024];
  for (int i = l; i < 1024; i += 64) cl[wv][i] = cbuf[(long)b * 1024 + i];
  for (int i = l; i < 1024; i += 64) {
    int t = i >> 3, kk = i & 7;
    el[wv][i] = eps_z[(long)t * (Bc * Kc) + b * 8 + kk];
  }
  float a2 = F[FO_A2 + l];   // A2[l>>3][l&7]
  __syncthreads();

  float z = zq0[l & 7];      // every lane holds z_prev[l&7]
  for (int t = 0; t < Tc; ++t) {
    float p = a2 * z;
    p += __shfl_xor(p, 1, 64);
    p += __shfl_xor(p, 2, 64);
    p += __shfl_xor(p, 4, 64);                  // group g=l>>3 holds sum_k1 A2[g][k1] z[k1]
    float zmu_l = __shfl(p, (l & 7) * 8, 64);   // lane l gets zmu_lin[l&7]
    float zl = zmu_l + cl[wv][t * 8 + (l & 7)]; // z_logits
    float zt = zl + el[wv][t * 8 + (l & 7)];    // z_sample

    // sparsemax over 8 values (all lanes redundantly)
    float v0 = __shfl(zt, 0, 64), v1 = __shfl(zt, 1, 64), v2 = __shfl(zt, 2, 64), v3 = __shfl(zt, 3, 64);
    float v4 = __shfl(zt, 4, 64), v5 = __shfl(zt, 5, 64), v6 = __shfl(zt, 6, 64), v7 = __shfl(zt, 7, 64);
    CASD(v0, v1); CASD(v2, v3); CASD(v4, v5); CASD(v6, v7);
    CASD(v0, v2); CASD(v1, v3); CASD(v4, v6); CASD(v5, v7);
    CASD(v1, v2); CASD(v5, v6);
    CASD(v0, v4); CASD(v1, v5); CASD(v2, v6); CASD(v3, v7);
    CASD(v2, v4); CASD(v3, v5);
    CASD(v1, v2); CASD(v3, v4); CASD(v5, v6);   // v0 >= v1 >= ... >= v7
    float s0 = v0, s1 = s0 + v1, s2 = s1 + v2, s3 = s2 + v3;
    float s4 = s3 + v4, s5 = s4 + v5, s6 = s5 + v6, s7 = s6 + v7;
    int kz = 1;
    kz += (2.0f * v1 > s1 - 1.0f) ? 1 : 0;
    kz += (3.0f * v2 > s2 - 1.0f) ? 1 : 0;
    kz += (4.0f * v3 > s3 - 1.0f) ? 1 : 0;
    kz += (5.0f * v4 > s4 - 1.0f) ? 1 : 0;
    kz += (6.0f * v5 > s5 - 1.0f) ? 1 : 0;
    kz += (7.0f * v6 > s6 - 1.0f) ? 1 : 0;
    kz += (8.0f * v7 > s7 - 1.0f) ? 1 : 0;
    float csel = s0 - 1.0f;
    csel = (kz > 1) ? s1 - 1.0f : csel;
    csel = (kz > 2) ? s2 - 1.0f : csel;
    csel = (kz > 3) ? s3 - 1.0f : csel;
    csel = (kz > 4) ? s4 - 1.0f : csel;
    csel = (kz > 5) ? s5 - 1.0f : csel;
    csel = (kz > 6) ? s6 - 1.0f : csel;
    csel = (kz > 7) ? s7 - 1.0f : csel;
    float tau = csel / (float)kz;
    float wk = fmaxf(zt - tau, 0.0f);

    if (l < 8) {
      long r = (long)b * Tc + t;
      out[O_ZL + r * 8 + l] = zl;
      out[O_ZS + r * 8 + l] = zt;
      wbuf[r * 8 + l] = wk;
    }
    z = zt;
  }
}

// ---------------- S5b: x_sample = sum_k w * mu + eps_x ----------------
__global__ void k_xsample(const float* __restrict__ wbuf, const float* __restrict__ eps_x,
                          float* __restrict__ out)
{
  long idx = (long)blockIdx.x * 256 + threadIdx.x;
  if (idx >= (long)Rc * Xc) return;
  long r = idx >> 6;          // b*T + t
  int x = (int)(idx & 63);
  long b = r >> 7;
  long t = r & 127;
  float s = eps_x[(t * Bc + b) * 64 + x];
#pragma unroll
  for (int k = 0; k < 8; ++k)
    s += wbuf[r * 8 + k] * out[O_QMU + ((long)k * Rc + r) * 64 + x];
  out[O_XS + idx] = s;
}

// ---------------- launch ----------------
extern "C" void kernel_launch(void* const* d_in, const int* in_sizes, int n_in,
                              void* d_out, int out_size, void* d_ws, size_t ws_size,
                              hipStream_t stream) {
  (void)in_sizes; (void)n_in; (void)out_size; (void)ws_size;
  const float* data   = (const float*)d_in[0];
  const float* eps_qx = (const float*)d_in[1];
  const float* eps_z  = (const float*)d_in[2];
  const float* eps_x  = (const float*)d_in[3];
  const float* yWih   = (const float*)d_in[4];
  const float* yWhh   = (const float*)d_in[5];
  const float* ybih   = (const float*)d_in[6];
  const float* ybhh   = (const float*)d_in[7];
  const float* yh0    = (const float*)d_in[8];
  const float* yWmu   = (const float*)d_in[9];
  const float* ybmu   = (const float*)d_in[10];
  const float* xWih   = (const float*)d_in[11];
  const float* xWhh   = (const float*)d_in[12];
  const float* xbih   = (const float*)d_in[13];
  const float* xbhh   = (const float*)d_in[14];
  const float* xh0    = (const float*)d_in[15];
  const float* dsW    = (const float*)d_in[16];
  const float* dsb    = (const float*)d_in[17];
  const float* cbW1   = (const float*)d_in[18];
  const float* cbb1   = (const float*)d_in[19];
  const float* cbW2   = (const float*)d_in[20];
  const float* cbb2   = (const float*)d_in[21];
  const float* zq0    = (const float*)d_in[22];

  u16*   W = (u16*)d_ws;
  float* F = (float*)((char*)d_ws + U16_BYTES);
  float* out = (float*)d_out;

  hipLaunchKernelGGL(k_prep, dim3(1024), dim3(256), 0, stream,
                     data, yWih, yWhh, yWmu, xWih, xWhh, ybih, ybhh, xbih, xbhh, W, F, out);
  hipLaunchKernelGGL(k_prep2, dim3(129), dim3(256), 0, stream,
                     dsW, dsb, cbW1, cbb1, cbW2, cbb2, W, F);
  hipLaunchKernelGGL(k_g1, dim3(128, 8), dim3(256), 0, stream, W, F, W + OFF_BUF1);
  hipLaunchKernelGGL(k_rnn, dim3(4, 8), dim3(256), 0, stream, W + OFF_BUF1, W + OFF_YWHH, yh0);
  hipLaunchKernelGGL(k_g2, dim3(128, 8), dim3(256), 0, stream,
                     W, W + OFF_BUF1, ybmu, eps_qx, out, W + OFF_QX);
  hipLaunchKernelGGL(k_g3, dim3(128, 8), dim3(256), 0, stream, W, W + OFF_QX, F, W + OFF_BUF2);
  hipLaunchKernelGGL(k_rnn, dim3(4, 8), dim3(256), 0, stream, W + OFF_BUF2, W + OFF_XWHH, xh0);
  hipLaunchKernelGGL(k_g4, dim3(128), dim3(256), 0, stream, W, W + OFF_BUF2, F, F + FO_C);
  hipLaunchKernelGGL(k_zchain, dim3(16), dim3(256), 0, stream, F, F + FO_C, eps_z, zq0, out, F + FO_W);
  hipLaunchKernelGGL(k_xsample, dim3(2048), dim3(256), 0, stream, F + FO_W, eps_x, out);
}